// Round 10
// baseline (171.555 us; speedup 1.0000x reference)
//
#include <hip/hip_runtime.h>

#define LTOT 110592   // 48*48*48
#define EPSV 1e-5f

typedef _Float16 f16;
typedef __attribute__((ext_vector_type(4))) _Float16 f16x4;
typedef __attribute__((ext_vector_type(8))) _Float16 f16x8;
typedef __attribute__((ext_vector_type(4))) float f32x4;

#define MFMA16(a, b, c) __builtin_amdgcn_mfma_f32_16x16x32_f16(a, b, c, 0, 0, 0)
#define SWC(c) ((((c) ^ ((c) >> 3)) & 7) << 3)
// LDS-visibility-only barrier: does not drain vmcnt, prefetch stays in flight.
#define BAR_LGKM() do { asm volatile("s_waitcnt lgkmcnt(0)" ::: "memory"); \
                        __builtin_amdgcn_s_barrier(); } while (0)

__device__ __forceinline__ f16x8 ld_w8(const float* p) {
  const float4 a = *(const float4*)p;
  const float4 b = *(const float4*)(p + 4);
  f16x8 f;
  f[0] = (f16)a.x; f[1] = (f16)a.y; f[2] = (f16)a.z; f[3] = (f16)a.w;
  f[4] = (f16)b.x; f[5] = (f16)b.y; f[6] = (f16)b.z; f[7] = (f16)b.w;
  return f;
}

// ============ P1: BmT,V proj (MFMA); e->EL; av-softmax->av_g; Mt += EL@XC ====
// grid (432, B), 4 tiles of 64 cols. Single X read/tile + reg prefetch.
// 49.3KB LDS -> 3 blocks/CU (single-X-read makes this safe, unlike r6).
__global__ __launch_bounds__(256, 3) void p1_proj_m(
    const float* __restrict__ x,
    const float* __restrict__ WB_, const float* __restrict__ bB_,
    const float* __restrict__ WV_, const float* __restrict__ bV_,
    f16* __restrict__ av_g, float* __restrict__ mpart, float* __restrict__ separt)
{
  __shared__ __align__(16) f16 XT[64 * 128];  // [l][c^((l&7)<<3)]
  __shared__ __align__(16) f16 XC[128 * 64];  // [c][l^SWC(c)]
  __shared__ __align__(16) f16 EL[64 * 64];   // [n][l^((n&7)<<3)]
  __shared__ __align__(16) f16 AVT[64 * 64];  // [l][n^((l&7)<<3)] (unscaled exp)
  __shared__ float colp[4][64];
  const int tid = threadIdx.x, b = blockIdx.y, blk = blockIdx.x;
  const int ln = tid & 63, w = tid >> 6, g = ln >> 4;

  const int nB = w * 16 + (ln & 15);
  f16x8 wbf[4], wvf[4];
  #pragma unroll
  for (int ks = 0; ks < 4; ++ks) {
    wbf[ks] = ld_w8(&WB_[nB * 128 + ks * 32 + g * 8]);
    wvf[ks] = ld_w8(&WV_[nB * 128 + ks * 32 + g * 8]);
  }
  const float sB = bB_[nB];
  float biasV[4];
  #pragma unroll
  for (int r = 0; r < 4; ++r) biasV[r] = bV_[w * 16 + g * 4 + r];

  f32x4 macc[8];
  #pragma unroll
  for (int i = 0; i < 8; ++i) macc[i] = (f32x4){0.f, 0.f, 0.f, 0.f};
  float se = 0.f;

  const int co = tid & 15, LQ = tid >> 4;  // thread covers c=co*8..+8, l=LQ*4..+4
  const size_t xb = (size_t)b * 128 * LTOT;

  float4 xr[8];
  {  // prologue: load tile 0
    const int l0 = blk * 256;
    #pragma unroll
    for (int j = 0; j < 8; ++j)
      xr[j] = *(const float4*)&x[xb + (size_t)(co * 8 + j) * LTOT + l0 + LQ * 4];
  }

  for (int t = 0; t < 4; ++t) {
    const int l0 = (blk * 4 + t) * 64;
    BAR_LGKM();   // prev tile's MFMAs done reading XT/XC
    // ---- stage from registers: XT [l][c] + XC [c][l] ----
    #pragma unroll
    for (int i = 0; i < 4; ++i) {
      const int l = LQ * 4 + i;
      f16x8 v;
      #pragma unroll
      for (int j = 0; j < 8; ++j) v[j] = (f16)(((const float*)&xr[j])[i]);
      *(f16x8*)&XT[l * 128 + ((co * 8) ^ ((l & 7) << 3))] = v;
    }
    #pragma unroll
    for (int j = 0; j < 8; ++j) {
      const int c = co * 8 + j;
      f16x4 q;
      q[0] = (f16)xr[j].x; q[1] = (f16)xr[j].y;
      q[2] = (f16)xr[j].z; q[3] = (f16)xr[j].w;
      *(f16x4*)&XC[c * 64 + ((LQ * 4) ^ SWC(c))] = q;
    }
    BAR_LGKM();   // stage visible; prefetch loads NOT drained
    // ---- prefetch next tile into regs (latency hidden under compute) ----
    if (t < 3) {
      const int l0n = l0 + 64;
      #pragma unroll
      for (int j = 0; j < 8; ++j)
        xr[j] = *(const float4*)&x[xb + (size_t)(co * 8 + j) * LTOT + l0n + LQ * 4];
    }
    // ---- proj: BmT (A=XT,B=WB) and V (A=WV,B=XT) share XT frags ----
    f32x4 aB[4], aV[4];
    #pragma unroll
    for (int lt = 0; lt < 4; ++lt) {
      aB[lt] = (f32x4){0.f, 0.f, 0.f, 0.f};
      aV[lt] = (f32x4){0.f, 0.f, 0.f, 0.f};
      const int l = lt * 16 + (ln & 15);
      #pragma unroll
      for (int ks = 0; ks < 4; ++ks) {
        const f16x8 xf = *(const f16x8*)&XT[l * 128 + (((ks * 4 + g) * 8) ^ ((l & 7) << 3))];
        aB[lt] = MFMA16(xf, wbf[ks], aB[lt]);
        aV[lt] = MFMA16(wvf[ks], xf, aV[lt]);
      }
    }
    // ---- e = exp(BmT + bias) -> EL (f16x4), sumexp ----
    #pragma unroll
    for (int lt = 0; lt < 4; ++lt) {
      f16x4 ev4;
      #pragma unroll
      for (int r = 0; r < 4; ++r) {
        const float e = __expf(aB[lt][r] + sB);
        se += e;
        ev4[r] = (f16)e;
      }
      const int lq = lt * 16 + g * 4;
      *(f16x4*)&EL[nB * 64 + (lq ^ ((nB & 7) << 3))] = ev4;
    }
    // ---- ev = exp(V + bias) -> AVT (unscaled), column-sum partials ----
    float cs[4];
    #pragma unroll
    for (int ct = 0; ct < 4; ++ct) {
      f16x4 av4;
      float s = 0.f;
      #pragma unroll
      for (int r = 0; r < 4; ++r) {
        const float e = __expf(aV[ct][r] + biasV[r]);
        s += e;
        av4[r] = (f16)e;
      }
      cs[ct] = s;
      const int l = ct * 16 + (ln & 15);
      *(f16x4*)&AVT[l * 64 + ((w * 16 + g * 4) ^ ((l & 7) << 3))] = av4;
    }
    #pragma unroll
    for (int ct = 0; ct < 4; ++ct) {
      cs[ct] += __shfl_xor(cs[ct], 16);
      cs[ct] += __shfl_xor(cs[ct], 32);
    }
    {
      const float v = (g == 0) ? cs[0] : (g == 1) ? cs[1] : (g == 2) ? cs[2] : cs[3];
      colp[w][g * 16 + (ln & 15)] = v;
    }
    BAR_LGKM();
    // ---- scale + store av tile to global [l][n] ----
    {
      const int l = tid >> 2, q = tid & 3;
      const float rs = 1.f / (colp[0][l] + colp[1][l] + colp[2][l] + colp[3][l]);
      f16x8 a0 = *(const f16x8*)&AVT[l * 64 + ((q * 16) ^ ((l & 7) << 3))];
      f16x8 a1 = *(const f16x8*)&AVT[l * 64 + ((q * 16 + 8) ^ ((l & 7) << 3))];
      #pragma unroll
      for (int j = 0; j < 8; ++j) {
        a0[j] = (f16)((float)a0[j] * rs);
        a1[j] = (f16)((float)a1[j] * rs);
      }
      f16* gp = av_g + ((size_t)b * LTOT + l0 + l) * 64 + q * 16;
      *(f16x8*)&gp[0] = a0;
      *(f16x8*)&gp[8] = a1;
    }
    // ---- Mt[n][c] += EL(A) @ XC(B), K=64 ----
    {
      f16x8 el[2];
      #pragma unroll
      for (int ks = 0; ks < 2; ++ks)
        el[ks] = *(const f16x8*)&EL[nB * 64 + ((ks * 32 + g * 8) ^ ((nB & 7) << 3))];
      #pragma unroll
      for (int cblk = 0; cblk < 8; ++cblk) {
        const int c = cblk * 16 + (ln & 15);
        #pragma unroll
        for (int ks = 0; ks < 2; ++ks) {
          const f16x8 xcf = *(const f16x8*)&XC[c * 64 + ((ks * 32 + g * 8) ^ SWC(c))];
          macc[cblk] = MFMA16(el[ks], xcf, macc[cblk]);
        }
      }
    }
  }
  // ---- write Mt partial [n][c] + sumexp partial ----
  float* mp = mpart + (size_t)(b * 432 + blk) * 8192;
  #pragma unroll
  for (int cblk = 0; cblk < 8; ++cblk)
    #pragma unroll
    for (int r = 0; r < 4; ++r)
      mp[(w * 16 + g * 4 + r) * 128 + cblk * 16 + (ln & 15)] = macc[cblk][r];
  se += __shfl_xor(se, 16);
  se += __shfl_xor(se, 32);
  if (ln < 16) separt[(size_t)(b * 432 + blk) * 64 + w * 16 + ln] = se;
}

// ============ P2a: Mt partials 432 -> 8 segs; sumexp 432 -> 1 ================
__global__ void p2a(const float* __restrict__ mpart, const float* __restrict__ separt,
                    float* __restrict__ mpart2, float* __restrict__ sesum)
{
  const int b = blockIdx.y, bx = blockIdx.x, tid = threadIdx.x;
  if (bx < 256) {
    const int seg = bx >> 5, chunk = bx & 31;
    const int idx = chunk * 256 + tid;
    float s = 0.f;
    for (int j = 0; j < 54; ++j)
      s += mpart[(size_t)(b * 432 + seg * 54 + j) * 8192 + idx];
    mpart2[(size_t)(b * 8 + seg) * 8192 + idx] = s;
  } else if (tid < 64) {
    float s = 0.f;
    for (int k = 0; k < 432; ++k) s += separt[(size_t)(b * 432 + k) * 64 + tid];
    sesum[b * 64 + tid] = s;
  }
}

// ============ P2a2: 8 segs -> msum [n][c] ====================================
__global__ void p2a2(const float* __restrict__ mpart2, float* __restrict__ msum)
{
  const int b = blockIdx.y;
  const int idx = blockIdx.x * 256 + threadIdx.x;
  float s = 0.f;
  #pragma unroll
  for (int k = 0; k < 8; ++k) s += mpart2[(size_t)(b * 8 + k) * 8192 + idx];
  msum[(size_t)b * 8192 + idx] = s;
}

// ============ P2b: G[m,n] = (WA@M)/sesum + bA; f32 [m][n] + swizzled f16 =====
__global__ void p2b(const float* __restrict__ WA_, const float* __restrict__ bA_,
                    const float* __restrict__ msum, const float* __restrict__ sesum,
                    float* __restrict__ g32, f16* __restrict__ g16)
{
  const int b = blockIdx.y;
  const int idx = blockIdx.x * 256 + threadIdx.x;
  const int m = idx >> 6, n = idx & 63;
  float s = 0.f;
  #pragma unroll 4
  for (int c = 0; c < 128; ++c) s += WA_[m * 128 + c] * msum[(size_t)b * 8192 + n * 128 + c];
  const float gv = s / sesum[b * 64 + n] + bA_[m];
  g32[(size_t)b * 8192 + m * 64 + n] = gv;
  g16[(size_t)b * 8192 + m * 64 + (n ^ ((m & 7) << 3))] = (f16)gv;
}

// ============ P3: C = av@av^T, mu = row-sums (reads av_g) ====================
// grid (216, B), 8 tiles each.
__global__ __launch_bounds__(256, 2) void p3_cov(
    const f16* __restrict__ av_g, float* __restrict__ cpart, float* __restrict__ mupart)
{
  __shared__ __align__(16) f16 AV[64 * 64];  // [n][l^((n&7)<<3)]
  const int tid = threadIdx.x, b = blockIdx.y, blk = blockIdx.x;
  const int ln = tid & 63, w = tid >> 6, g = ln >> 4;
  const int nq4 = (tid & 15) * 4, lq4 = (tid >> 4) * 4;  // stage: 4l x 4n
  const int nmu = tid >> 2, qmu = tid & 3;

  f32x4 cacc[4];
  #pragma unroll
  for (int j = 0; j < 4; ++j) cacc[j] = (f32x4){0.f, 0.f, 0.f, 0.f};
  float muacc = 0.f;

  for (int t = 0; t < 8; ++t) {
    const int l0 = (blk * 8 + t) * 64;
    __syncthreads();
    {  // stage: read [l][n] quads, transpose in regs, write [n][l] quads
      f16x4 rd[4];
      #pragma unroll
      for (int i = 0; i < 4; ++i)
        rd[i] = *(const f16x4*)&av_g[((size_t)b * LTOT + l0 + lq4 + i) * 64 + nq4];
      #pragma unroll
      for (int j = 0; j < 4; ++j) {
        const int n = nq4 + j;
        f16x4 wr;
        #pragma unroll
        for (int i = 0; i < 4; ++i) wr[i] = rd[i][j];
        *(f16x4*)&AV[n * 64 + (lq4 ^ ((n & 7) << 3))] = wr;
      }
    }
    __syncthreads();
    {  // mu partial: row sums
      const f16x8 a0 = *(const f16x8*)&AV[nmu * 64 + ((qmu * 16) ^ ((nmu & 7) << 3))];
      const f16x8 a1 = *(const f16x8*)&AV[nmu * 64 + ((qmu * 16 + 8) ^ ((nmu & 7) << 3))];
      #pragma unroll
      for (int j = 0; j < 8; ++j) muacc += (float)a0[j] + (float)a1[j];
    }
    // C MFMA: wave w owns rows n = w*16..+16
    const int nA = w * 16 + (ln & 15);
    f16x8 caf[2];
    #pragma unroll
    for (int ks = 0; ks < 2; ++ks)
      caf[ks] = *(const f16x8*)&AV[nA * 64 + ((ks * 32 + g * 8) ^ ((nA & 7) << 3))];
    #pragma unroll
    for (int nct = 0; nct < 4; ++nct) {
      const int nb = nct * 16 + (ln & 15);
      #pragma unroll
      for (int ks = 0; ks < 2; ++ks) {
        const f16x8 cbf = *(const f16x8*)&AV[nb * 64 + ((ks * 32 + g * 8) ^ ((nb & 7) << 3))];
        cacc[nct] = MFMA16(caf[ks], cbf, cacc[nct]);
      }
    }
  }
  float* cp = cpart + (size_t)(b * 216 + blk) * 4096;
  #pragma unroll
  for (int nct = 0; nct < 4; ++nct)
    #pragma unroll
    for (int r = 0; r < 4; ++r)
      cp[(w * 16 + g * 4 + r) * 64 + nct * 16 + (ln & 15)] = cacc[nct][r];
  muacc += __shfl_xor(muacc, 1);
  muacc += __shfl_xor(muacc, 2);
  if (qmu == 0) mupart[(size_t)(b * 216 + blk) * 64 + nmu] = muacc;
}

// ============ P4a: reduce C partials + mu partials ===========================
__global__ void p4a(const float* __restrict__ cpart, const float* __restrict__ mupart,
                    float* __restrict__ csum, float* __restrict__ musum)
{
  const int b = blockIdx.y, bx = blockIdx.x, tid = threadIdx.x;
  if (bx < 64) {
    const int idx = bx * 64 + (tid >> 2), q = tid & 3;
    float s = 0.f;
    for (int k = q; k < 216; k += 4) s += cpart[(size_t)(b * 216 + k) * 4096 + idx];
    s += __shfl_xor(s, 1);
    s += __shfl_xor(s, 2);
    if (q == 0) csum[(size_t)b * 4096 + idx] = s;
  } else if (tid < 64) {
    float s = 0.f;
    for (int k = 0; k < 216; ++k) s += mupart[(size_t)(b * 216 + k) * 64 + tid];
    musum[b * 64 + tid] = s;
  }
}

// ============ P4b: mean = G@mu/L; E[Z^2] = (G C G^T)_mm / L -> mean,rsig =====
__global__ void p4b(const float* __restrict__ csum, const float* __restrict__ musum,
                    const float* __restrict__ g32, float* __restrict__ mr)
{
  __shared__ __align__(16) float CL[4096];
  __shared__ __align__(16) float GLs[32 * 68];
  __shared__ float MUL[64];
  const int tid = threadIdx.x, b = blockIdx.y, bx = blockIdx.x;
  #pragma unroll
  for (int k = 0; k < 16; ++k) CL[k * 256 + tid] = csum[(size_t)b * 4096 + k * 256 + tid];
  #pragma unroll
  for (int k = 0; k < 8; ++k) {
    const int idx = k * 256 + tid;
    const int m_ = idx >> 6, n_ = idx & 63;
    GLs[m_ * 68 + n_] = g32[(size_t)b * 8192 + (bx * 32 + m_) * 64 + n_];
  }
  if (tid < 64) MUL[tid] = musum[b * 64 + tid];
  __syncthreads();
  const int mrow = (tid >> 3) * 68, oct = tid & 7;
  float q = 0.f;
  #pragma unroll
  for (int q4 = 0; q4 < 2; ++q4) {
    const int npb = oct * 8 + q4 * 4;
    float t0 = 0.f, t1 = 0.f, t2 = 0.f, t3 = 0.f;
    #pragma unroll 8
    for (int n = 0; n < 64; ++n) {
      const float4 cv = *(const float4*)&CL[n * 64 + npb];
      const float gv = GLs[mrow + n];
      t0 += gv * cv.x; t1 += gv * cv.y; t2 += gv * cv.z; t3 += gv * cv.w;
    }
    const float4 gq = *(const float4*)&GLs[mrow + npb];
    q += t0 * gq.x + t1 * gq.y + t2 * gq.z + t3 * gq.w;
  }
  q += __shfl_xor(q, 1); q += __shfl_xor(q, 2); q += __shfl_xor(q, 4);
  if (oct == 0) {
    float meanq = 0.f;
    #pragma unroll 8
    for (int n = 0; n < 64; ++n) meanq += GLs[mrow + n] * MUL[n];
    const int m = bx * 32 + (tid >> 3);
    const float mean = meanq / (float)LTOT;
    const float var = fmaxf(q / (float)LTOT - mean * mean, 0.f);
    mr[(b * 128 + m) * 2] = mean;
    mr[(b * 128 + m) * 2 + 1] = rsqrtf(var + EPSV);
  }
}

// ============ P5: Z = G@av (MFMA), write normalized ==========================
// grid (432, B), 4 tiles each.
__global__ __launch_bounds__(256, 2) void p5_z(
    const f16* __restrict__ av_g, const f16* __restrict__ g16,
    const float* __restrict__ mr, float* __restrict__ out)
{
  __shared__ __align__(16) f16 AVT[64 * 64];  // [l][n^((l&7)<<3)]
  const int tid = threadIdx.x, b = blockIdx.y, blk = blockIdx.x;
  const int ln = tid & 63, w = tid >> 6, g = ln >> 4;
  const int lst = tid & 63, pst = tid >> 6;

  // G fragments: wave w owns m = w*32..+32 (2 mct of 16)
  f16x8 gf[2][2];
  float mean_[2][4], rsig_[2][4];
  #pragma unroll
  for (int mct = 0; mct < 2; ++mct) {
    const int mA = w * 32 + mct * 16 + (ln & 15);
    #pragma unroll
    for (int ks = 0; ks < 2; ++ks)
      gf[mct][ks] = *(const f16x8*)&g16[(size_t)b * 8192 + mA * 64 +
                                        (((ks * 4 + g) * 8) ^ ((mA & 7) << 3))];
    #pragma unroll
    for (int r = 0; r < 4; ++r) {
      const int m = w * 32 + mct * 16 + g * 4 + r;
      mean_[mct][r] = mr[(b * 128 + m) * 2];
      rsig_[mct][r] = mr[(b * 128 + m) * 2 + 1];
    }
  }

  for (int t = 0; t < 4; ++t) {
    const int l0 = (blk * 4 + t) * 64;
    __syncthreads();
    {  // stage av tile: straight vector copy with swizzle
      const f16* gp = av_g + ((size_t)b * LTOT + l0 + lst) * 64 + pst * 16;
      const f16x8 a0 = *(const f16x8*)&gp[0];
      const f16x8 a1 = *(const f16x8*)&gp[8];
      *(f16x8*)&AVT[lst * 64 + ((pst * 16) ^ ((lst & 7) << 3))] = a0;
      *(f16x8*)&AVT[lst * 64 + ((pst * 16 + 8) ^ ((lst & 7) << 3))] = a1;
    }
    __syncthreads();
    #pragma unroll
    for (int lt = 0; lt < 4; ++lt) {
      const int l = lt * 16 + (ln & 15);
      f16x8 avf[2];
      #pragma unroll
      for (int ks = 0; ks < 2; ++ks)
        avf[ks] = *(const f16x8*)&AVT[l * 64 + (((ks * 4 + g) * 8) ^ ((l & 7) << 3))];
      #pragma unroll
      for (int mct = 0; mct < 2; ++mct) {
        f32x4 z = {0.f, 0.f, 0.f, 0.f};
        #pragma unroll
        for (int ks = 0; ks < 2; ++ks) z = MFMA16(gf[mct][ks], avf[ks], z);
        #pragma unroll
        for (int r = 0; r < 4; ++r) {
          const int m = w * 32 + mct * 16 + g * 4 + r;
          out[(size_t)(b * 128 + m) * LTOT + l0 + l] =
              (z[r] - mean_[mct][r]) * rsig_[mct][r];
        }
      }
    }
  }
}

extern "C" void kernel_launch(void* const* d_in, const int* in_sizes, int n_in,
                              void* d_out, int out_size, void* d_ws, size_t ws_size,
                              hipStream_t stream)
{
  const float* x  = (const float*)d_in[0];
  const float* WA = (const float*)d_in[1];
  const float* bA = (const float*)d_in[2];
  const float* WB = (const float*)d_in[3];
  const float* bB = (const float*)d_in[4];
  const float* WV = (const float*)d_in[5];
  const float* bV = (const float*)d_in[6];
  float* out = (float*)d_out;

  float* w = (float*)d_ws;
  float* mpart  = w;                        // 2*432*8192 = 7,077,888 f
  float* mpart2 = mpart + 7077888;          // 2*8*8192
  float* separt = mpart2 + 131072;          // 2*432*64
  float* msum   = separt + 55296;           // 2*8192
  float* sesum  = msum + 16384;             // 128
  float* g32    = sesum + 128;              // 2*8192
  f16*   g16f   = (f16*)(g32 + 16384);      // 16,384 f16
  f16*   av_g   = g16f + 16384;             // 2*L*64 f16 = 14,155,776
  float* cpart  = (float*)(av_g + 14155776);// 2*216*4096 = 1,769,472 f
  float* mupart = cpart + 1769472;          // 2*216*64
  float* csum   = mupart + 27648;           // 2*4096
  float* musum  = csum + 8192;              // 128
  float* mr     = musum + 128;              // 512

  p1_proj_m<<<dim3(432, 2), 256, 0, stream>>>(x, WB, bB, WV, bV, av_g, mpart, separt);
  p2a<<<dim3(257, 2), 256, 0, stream>>>(mpart, separt, mpart2, sesum);
  p2a2<<<dim3(32, 2), 256, 0, stream>>>(mpart2, msum);
  p2b<<<dim3(32, 2), 256, 0, stream>>>(WA, bA, msum, sesum, g32, g16f);
  p3_cov<<<dim3(216, 2), 256, 0, stream>>>(av_g, cpart, mupart);
  p4a<<<dim3(65, 2), 256, 0, stream>>>(cpart, mupart, csum, musum);
  p4b<<<dim3(4, 2), 256, 0, stream>>>(csum, musum, g32, mr);
  p5_z<<<dim3(432, 2), 256, 0, stream>>>(av_g, g16f, mr, out);
}

// Round 11
// 149.202 us; speedup vs baseline: 1.1498x; 1.1498x over previous
//
#include <hip/hip_runtime.h>

#define LTOT 110592   // 48*48*48
#define EPSV 1e-5f

typedef _Float16 f16;
typedef __attribute__((ext_vector_type(4))) _Float16 f16x4;
typedef __attribute__((ext_vector_type(8))) _Float16 f16x8;
typedef __attribute__((ext_vector_type(4))) float f32x4;

#define MFMA16(a, b, c) __builtin_amdgcn_mfma_f32_16x16x32_f16(a, b, c, 0, 0, 0)
// XC swizzle: depends on both low and mid bits of c so that simultaneous
// writers (c strided by 8) AND simultaneous readers (c contiguous 16) spread.
#define SWC(c) ((((c) ^ ((c) >> 3)) & 7) << 3)

__device__ __forceinline__ f16x8 ld_w8(const float* p) {
  const float4 a = *(const float4*)p;
  const float4 b = *(const float4*)(p + 4);
  f16x8 f;
  f[0] = (f16)a.x; f[1] = (f16)a.y; f[2] = (f16)a.z; f[3] = (f16)a.w;
  f[4] = (f16)b.x; f[5] = (f16)b.y; f[6] = (f16)b.z; f[7] = (f16)b.w;
  return f;
}

// ============ P1: BmT,V proj (MFMA); e->EL; av-softmax->av_g; Mt += EL@XC ====
// grid (432, B), 4 tiles of 64 cols. Single X read/tile + reg prefetch (T14).
// LDS padded to 54.7KB -> exactly 2 blocks/CU (r6/r10: 3 blocks thrashes L2).
// r10 falsifier fired: p1 structure frozen at this (best-measured) config.
__global__ __launch_bounds__(256, 2) void p1_proj_m(
    const float* __restrict__ x,
    const float* __restrict__ WB_, const float* __restrict__ bB_,
    const float* __restrict__ WV_, const float* __restrict__ bV_,
    f16* __restrict__ av_g, float* __restrict__ mpart, float* __restrict__ separt)
{
  __shared__ __align__(16) f16 XT[64 * 128 + 2240];  // [l][c^((l&7)<<3)] (+pad)
  __shared__ __align__(16) f16 XC[128 * 64];  // [c][l^SWC(c)]
  __shared__ __align__(16) f16 EL[64 * 64];   // [n][l^((n&7)<<3)]
  __shared__ __align__(16) f16 AVT[64 * 64];  // [l][n^((l&7)<<3)] (unscaled exp)
  __shared__ float colp[4][64];
  const int tid = threadIdx.x, b = blockIdx.y, blk = blockIdx.x;
  const int ln = tid & 63, w = tid >> 6, g = ln >> 4;

  // W fragments (rows n = w*16 + (ln&15))
  const int nB = w * 16 + (ln & 15);
  f16x8 wbf[4], wvf[4];
  #pragma unroll
  for (int ks = 0; ks < 4; ++ks) {
    wbf[ks] = ld_w8(&WB_[nB * 128 + ks * 32 + g * 8]);
    wvf[ks] = ld_w8(&WV_[nB * 128 + ks * 32 + g * 8]);
  }
  const float sB = bB_[nB];
  float biasV[4];
  #pragma unroll
  for (int r = 0; r < 4; ++r) biasV[r] = bV_[w * 16 + g * 4 + r];

  f32x4 macc[8];
  #pragma unroll
  for (int i = 0; i < 8; ++i) macc[i] = (f32x4){0.f, 0.f, 0.f, 0.f};
  float se = 0.f;

  // staging thread map: c = co*8+j (j=0..7), l = LQ*4+i (i=0..3)
  const int co = tid & 15, LQ = tid >> 4;
  const size_t xb = (size_t)b * 128 * LTOT;

  float4 xr[8];
  {  // prologue: load tile 0
    const int l0 = blk * 256;
    #pragma unroll
    for (int j = 0; j < 8; ++j)
      xr[j] = *(const float4*)&x[xb + (size_t)(co * 8 + j) * LTOT + l0 + LQ * 4];
  }

  for (int t = 0; t < 4; ++t) {
    const int l0 = (blk * 4 + t) * 64;
    __syncthreads();   // prev tile's M-MFMA done reading XC
    // ---- stage from regs: XT [l][c] (4x f16x8) ----
    #pragma unroll
    for (int i = 0; i < 4; ++i) {
      const int l = LQ * 4 + i;
      f16x8 v;
      #pragma unroll
      for (int j = 0; j < 8; ++j) v[j] = (f16)(((const float*)&xr[j])[i]);
      *(f16x8*)&XT[l * 128 + ((co * 8) ^ ((l & 7) << 3))] = v;
    }
    // ---- stage from regs: XC [c][l] (8x f16x4, SWC swizzle) ----
    #pragma unroll
    for (int j = 0; j < 8; ++j) {
      const int c = co * 8 + j;
      f16x4 q;
      q[0] = (f16)xr[j].x; q[1] = (f16)xr[j].y;
      q[2] = (f16)xr[j].z; q[3] = (f16)xr[j].w;
      *(f16x4*)&XC[c * 64 + ((LQ * 4) ^ SWC(c))] = q;
    }
    __syncthreads();   // stage visible
    // ---- prefetch tile t+1 into regs: in flight across proj+exp ----
    if (t < 3) {
      const int l0n = l0 + 64;
      #pragma unroll
      for (int j = 0; j < 8; ++j)
        xr[j] = *(const float4*)&x[xb + (size_t)(co * 8 + j) * LTOT + l0n + LQ * 4];
    }
    // ---- proj: BmT (A=XT,B=WB) and V (A=WV,B=XT) share XT frags ----
    f32x4 aB[4], aV[4];
    #pragma unroll
    for (int lt = 0; lt < 4; ++lt) {
      aB[lt] = (f32x4){0.f, 0.f, 0.f, 0.f};
      aV[lt] = (f32x4){0.f, 0.f, 0.f, 0.f};
      const int l = lt * 16 + (ln & 15);
      #pragma unroll
      for (int ks = 0; ks < 4; ++ks) {
        const f16x8 xf = *(const f16x8*)&XT[l * 128 + (((ks * 4 + g) * 8) ^ ((l & 7) << 3))];
        aB[lt] = MFMA16(xf, wbf[ks], aB[lt]);
        aV[lt] = MFMA16(wvf[ks], xf, aV[lt]);
      }
    }
    // ---- e = exp(BmT + bias) -> EL (f16x4), sumexp ----
    #pragma unroll
    for (int lt = 0; lt < 4; ++lt) {
      f16x4 ev4;
      #pragma unroll
      for (int r = 0; r < 4; ++r) {
        const float e = __expf(aB[lt][r] + sB);
        se += e;
        ev4[r] = (f16)e;
      }
      const int lq = lt * 16 + g * 4;
      *(f16x4*)&EL[nB * 64 + (lq ^ ((nB & 7) << 3))] = ev4;
    }
    // ---- ev = exp(V + bias) -> AVT (unscaled), column-sum partials ----
    float cs[4];
    #pragma unroll
    for (int ct = 0; ct < 4; ++ct) {
      f16x4 av4;
      float s = 0.f;
      #pragma unroll
      for (int r = 0; r < 4; ++r) {
        const float e = __expf(aV[ct][r] + biasV[r]);
        s += e;
        av4[r] = (f16)e;
      }
      cs[ct] = s;
      const int l = ct * 16 + (ln & 15);
      *(f16x4*)&AVT[l * 64 + ((w * 16 + g * 4) ^ ((l & 7) << 3))] = av4;
    }
    #pragma unroll
    for (int ct = 0; ct < 4; ++ct) {
      cs[ct] += __shfl_xor(cs[ct], 16);
      cs[ct] += __shfl_xor(cs[ct], 32);
    }
    {
      const float v = (g == 0) ? cs[0] : (g == 1) ? cs[1] : (g == 2) ? cs[2] : cs[3];
      colp[w][g * 16 + (ln & 15)] = v;
    }
    __syncthreads();
    // ---- scale + store av tile to global [l][n] ----
    {
      const int l = tid >> 2, q = tid & 3;
      const float rs = 1.f / (colp[0][l] + colp[1][l] + colp[2][l] + colp[3][l]);
      f16x8 a0 = *(const f16x8*)&AVT[l * 64 + ((q * 16) ^ ((l & 7) << 3))];
      f16x8 a1 = *(const f16x8*)&AVT[l * 64 + ((q * 16 + 8) ^ ((l & 7) << 3))];
      #pragma unroll
      for (int j = 0; j < 8; ++j) {
        a0[j] = (f16)((float)a0[j] * rs);
        a1[j] = (f16)((float)a1[j] * rs);
      }
      f16* gp = av_g + ((size_t)b * LTOT + l0 + l) * 64 + q * 16;
      *(f16x8*)&gp[0] = a0;
      *(f16x8*)&gp[8] = a1;
    }
    // ---- Mt[n][c] += EL(A) @ XC(B), K=64 ----
    {
      f16x8 el[2];
      #pragma unroll
      for (int ks = 0; ks < 2; ++ks)
        el[ks] = *(const f16x8*)&EL[nB * 64 + ((ks * 32 + g * 8) ^ ((nB & 7) << 3))];
      #pragma unroll
      for (int cblk = 0; cblk < 8; ++cblk) {
        const int c = cblk * 16 + (ln & 15);
        #pragma unroll
        for (int ks = 0; ks < 2; ++ks) {
          const f16x8 xcf = *(const f16x8*)&XC[c * 64 + ((ks * 32 + g * 8) ^ SWC(c))];
          macc[cblk] = MFMA16(el[ks], xcf, macc[cblk]);
        }
      }
    }
  }
  // ---- write Mt partial [n][c] + sumexp partial ----
  float* mp = mpart + (size_t)(b * 432 + blk) * 8192;
  #pragma unroll
  for (int cblk = 0; cblk < 8; ++cblk)
    #pragma unroll
    for (int r = 0; r < 4; ++r)
      mp[(w * 16 + g * 4 + r) * 128 + cblk * 16 + (ln & 15)] = macc[cblk][r];
  se += __shfl_xor(se, 16);
  se += __shfl_xor(se, 32);
  if (ln < 16) separt[(size_t)(b * 432 + blk) * 64 + w * 16 + ln] = se;
}

// ============ P2a: Mt partials 432 -> 8 segs; sumexp 432 -> 1 ================
__global__ void p2a(const float* __restrict__ mpart, const float* __restrict__ separt,
                    float* __restrict__ mpart2, float* __restrict__ sesum)
{
  const int b = blockIdx.y, bx = blockIdx.x, tid = threadIdx.x;
  if (bx < 256) {
    const int seg = bx >> 5, chunk = bx & 31;
    const int idx = chunk * 256 + tid;
    float s = 0.f;
    #pragma unroll 4
    for (int j = 0; j < 54; ++j)
      s += mpart[(size_t)(b * 432 + seg * 54 + j) * 8192 + idx];
    mpart2[(size_t)(b * 8 + seg) * 8192 + idx] = s;
  } else if (tid < 64) {
    float s = 0.f;
    #pragma unroll 4
    for (int k = 0; k < 432; ++k) s += separt[(size_t)(b * 432 + k) * 64 + tid];
    sesum[b * 64 + tid] = s;
  }
}

// ============ P2a2: 8 segs -> msum [n][c] ====================================
__global__ void p2a2(const float* __restrict__ mpart2, float* __restrict__ msum)
{
  const int b = blockIdx.y;
  const int idx = blockIdx.x * 256 + threadIdx.x;
  float s = 0.f;
  #pragma unroll
  for (int k = 0; k < 8; ++k) s += mpart2[(size_t)(b * 8 + k) * 8192 + idx];
  msum[(size_t)b * 8192 + idx] = s;
}

// ============ P2b: G[m,n] = (WA@M)/sesum + bA; f32 [m][n] + swizzled f16 =====
__global__ void p2b(const float* __restrict__ WA_, const float* __restrict__ bA_,
                    const float* __restrict__ msum, const float* __restrict__ sesum,
                    float* __restrict__ g32, f16* __restrict__ g16)
{
  const int b = blockIdx.y;
  const int idx = blockIdx.x * 256 + threadIdx.x;
  const int m = idx >> 6, n = idx & 63;
  float s = 0.f;
  #pragma unroll 4
  for (int c = 0; c < 128; ++c) s += WA_[m * 128 + c] * msum[(size_t)b * 8192 + n * 128 + c];
  const float gv = s / sesum[b * 64 + n] + bA_[m];
  g32[(size_t)b * 8192 + m * 64 + n] = gv;
  g16[(size_t)b * 8192 + m * 64 + (n ^ ((m & 7) << 3))] = (f16)gv;
}

// ============ P3: C = av@av^T, mu = row-sums (reads av_g) ====================
// grid (216, B), 8 tiles each.
__global__ __launch_bounds__(256, 2) void p3_cov(
    const f16* __restrict__ av_g, float* __restrict__ cpart, float* __restrict__ mupart)
{
  __shared__ __align__(16) f16 AV[64 * 64];  // [n][l^((n&7)<<3)]
  const int tid = threadIdx.x, b = blockIdx.y, blk = blockIdx.x;
  const int ln = tid & 63, w = tid >> 6, g = ln >> 4;
  const int nq4 = (tid & 15) * 4, lq4 = (tid >> 4) * 4;  // stage: 4l x 4n
  const int nmu = tid >> 2, qmu = tid & 3;

  f32x4 cacc[4];
  #pragma unroll
  for (int j = 0; j < 4; ++j) cacc[j] = (f32x4){0.f, 0.f, 0.f, 0.f};
  float muacc = 0.f;

  for (int t = 0; t < 8; ++t) {
    const int l0 = (blk * 8 + t) * 64;
    __syncthreads();
    {  // stage: read [l][n] quads, transpose in regs, write [n][l] quads
      f16x4 rd[4];
      #pragma unroll
      for (int i = 0; i < 4; ++i)
        rd[i] = *(const f16x4*)&av_g[((size_t)b * LTOT + l0 + lq4 + i) * 64 + nq4];
      #pragma unroll
      for (int j = 0; j < 4; ++j) {
        const int n = nq4 + j;
        f16x4 wr;
        #pragma unroll
        for (int i = 0; i < 4; ++i) wr[i] = rd[i][j];
        *(f16x4*)&AV[n * 64 + (lq4 ^ ((n & 7) << 3))] = wr;
      }
    }
    __syncthreads();
    {  // mu partial: row sums
      const f16x8 a0 = *(const f16x8*)&AV[nmu * 64 + ((qmu * 16) ^ ((nmu & 7) << 3))];
      const f16x8 a1 = *(const f16x8*)&AV[nmu * 64 + ((qmu * 16 + 8) ^ ((nmu & 7) << 3))];
      #pragma unroll
      for (int j = 0; j < 8; ++j) muacc += (float)a0[j] + (float)a1[j];
    }
    // C MFMA: wave w owns rows n = w*16..+16
    const int nA = w * 16 + (ln & 15);
    f16x8 caf[2];
    #pragma unroll
    for (int ks = 0; ks < 2; ++ks)
      caf[ks] = *(const f16x8*)&AV[nA * 64 + ((ks * 32 + g * 8) ^ ((nA & 7) << 3))];
    #pragma unroll
    for (int nct = 0; nct < 4; ++nct) {
      const int nb = nct * 16 + (ln & 15);
      #pragma unroll
      for (int ks = 0; ks < 2; ++ks) {
        const f16x8 cbf = *(const f16x8*)&AV[nb * 64 + ((ks * 32 + g * 8) ^ ((nb & 7) << 3))];
        cacc[nct] = MFMA16(caf[ks], cbf, cacc[nct]);
      }
    }
  }
  float* cp = cpart + (size_t)(b * 216 + blk) * 4096;
  #pragma unroll
  for (int nct = 0; nct < 4; ++nct)
    #pragma unroll
    for (int r = 0; r < 4; ++r)
      cp[(w * 16 + g * 4 + r) * 64 + nct * 16 + (ln & 15)] = cacc[nct][r];
  muacc += __shfl_xor(muacc, 1);
  muacc += __shfl_xor(muacc, 2);
  if (qmu == 0) mupart[(size_t)(b * 216 + blk) * 64 + nmu] = muacc;
}

// ============ P4a: reduce C partials + mu partials ===========================
__global__ void p4a(const float* __restrict__ cpart, const float* __restrict__ mupart,
                    float* __restrict__ csum, float* __restrict__ musum)
{
  const int b = blockIdx.y, bx = blockIdx.x, tid = threadIdx.x;
  if (bx < 64) {
    const int idx = bx * 64 + (tid >> 2), q = tid & 3;
    float s = 0.f;
    for (int k = q; k < 216; k += 4) s += cpart[(size_t)(b * 216 + k) * 4096 + idx];
    s += __shfl_xor(s, 1);
    s += __shfl_xor(s, 2);
    if (q == 0) csum[(size_t)b * 4096 + idx] = s;
  } else if (tid < 64) {
    float s = 0.f;
    for (int k = 0; k < 216; ++k) s += mupart[(size_t)(b * 216 + k) * 64 + tid];
    musum[b * 64 + tid] = s;
  }
}

// ============ P4b: mean = G@mu/L; E[Z^2] = (G C G^T)_mm / L -> mean,rsig =====
__global__ void p4b(const float* __restrict__ csum, const float* __restrict__ musum,
                    const float* __restrict__ g32, float* __restrict__ mr)
{
  __shared__ __align__(16) float CL[4096];
  __shared__ __align__(16) float GLs[32 * 68];
  __shared__ float MUL[64];
  const int tid = threadIdx.x, b = blockIdx.y, bx = blockIdx.x;
  #pragma unroll
  for (int k = 0; k < 16; ++k) CL[k * 256 + tid] = csum[(size_t)b * 4096 + k * 256 + tid];
  #pragma unroll
  for (int k = 0; k < 8; ++k) {
    const int idx = k * 256 + tid;
    const int m_ = idx >> 6, n_ = idx & 63;
    GLs[m_ * 68 + n_] = g32[(size_t)b * 8192 + (bx * 32 + m_) * 64 + n_];
  }
  if (tid < 64) MUL[tid] = musum[b * 64 + tid];
  __syncthreads();
  const int mrow = (tid >> 3) * 68, oct = tid & 7;
  float q = 0.f;
  #pragma unroll
  for (int q4 = 0; q4 < 2; ++q4) {
    const int npb = oct * 8 + q4 * 4;
    float t0 = 0.f, t1 = 0.f, t2 = 0.f, t3 = 0.f;
    #pragma unroll 8
    for (int n = 0; n < 64; ++n) {
      const float4 cv = *(const float4*)&CL[n * 64 + npb];
      const float gv = GLs[mrow + n];
      t0 += gv * cv.x; t1 += gv * cv.y; t2 += gv * cv.z; t3 += gv * cv.w;
    }
    const float4 gq = *(const float4*)&GLs[mrow + npb];
    q += t0 * gq.x + t1 * gq.y + t2 * gq.z + t3 * gq.w;
  }
  q += __shfl_xor(q, 1); q += __shfl_xor(q, 2); q += __shfl_xor(q, 4);
  if (oct == 0) {
    float meanq = 0.f;
    #pragma unroll 8
    for (int n = 0; n < 64; ++n) meanq += GLs[mrow + n] * MUL[n];
    const int m = bx * 32 + (tid >> 3);
    const float mean = meanq / (float)LTOT;
    const float var = fmaxf(q / (float)LTOT - mean * mean, 0.f);
    mr[(b * 128 + m) * 2] = mean;
    mr[(b * 128 + m) * 2 + 1] = rsqrtf(var + EPSV);
  }
}

// ============ P5: Z = G@av (MFMA), LDS-free: B-frags direct from av_g ========
// grid (432, B), 4 tiles each. av_g[l][n] is already fragment-contiguous
// (8 n at fixed l = 16B) -> no staging, no barriers, 4 blocks/CU.
__global__ __launch_bounds__(256, 4) void p5_z(
    const f16* __restrict__ av_g, const f16* __restrict__ g16,
    const float* __restrict__ mr, float* __restrict__ out)
{
  const int tid = threadIdx.x, b = blockIdx.y, blk = blockIdx.x;
  const int ln = tid & 63, w = tid >> 6, g = ln >> 4;

  // G fragments: wave w owns m = w*32..+32 (2 mct of 16)
  f16x8 gf[2][2];
  float mean_[2][4], rsig_[2][4];
  #pragma unroll
  for (int mct = 0; mct < 2; ++mct) {
    const int mA = w * 32 + mct * 16 + (ln & 15);
    #pragma unroll
    for (int ks = 0; ks < 2; ++ks)
      gf[mct][ks] = *(const f16x8*)&g16[(size_t)b * 8192 + mA * 64 +
                                        (((ks * 4 + g) * 8) ^ ((mA & 7) << 3))];
    #pragma unroll
    for (int r = 0; r < 4; ++r) {
      const int m = w * 32 + mct * 16 + g * 4 + r;
      mean_[mct][r] = mr[(b * 128 + m) * 2];
      rsig_[mct][r] = mr[(b * 128 + m) * 2 + 1];
    }
  }

  #pragma unroll
  for (int t = 0; t < 4; ++t) {
    const int l0 = (blk * 4 + t) * 64;
    #pragma unroll
    for (int lt = 0; lt < 4; ++lt) {
      const int l = lt * 16 + (ln & 15);
      const f16* ap = av_g + ((size_t)b * LTOT + l0 + l) * 64;
      f16x8 avf[2];
      #pragma unroll
      for (int ks = 0; ks < 2; ++ks)
        avf[ks] = *(const f16x8*)&ap[(ks * 4 + g) * 8];
      #pragma unroll
      for (int mct = 0; mct < 2; ++mct) {
        f32x4 z = {0.f, 0.f, 0.f, 0.f};
        #pragma unroll
        for (int ks = 0; ks < 2; ++ks) z = MFMA16(gf[mct][ks], avf[ks], z);
        #pragma unroll
        for (int r = 0; r < 4; ++r) {
          const int m = w * 32 + mct * 16 + g * 4 + r;
          out[(size_t)(b * 128 + m) * LTOT + l0 + l] =
              (z[r] - mean_[mct][r]) * rsig_[mct][r];
        }
      }
    }
  }
}

extern "C" void kernel_launch(void* const* d_in, const int* in_sizes, int n_in,
                              void* d_out, int out_size, void* d_ws, size_t ws_size,
                              hipStream_t stream)
{
  const float* x  = (const float*)d_in[0];
  const float* WA = (const float*)d_in[1];
  const float* bA = (const float*)d_in[2];
  const float* WB = (const float*)d_in[3];
  const float* bB = (const float*)d_in[4];
  const float* WV = (const float*)d_in[5];
  const float* bV = (const float*)d_in[6];
  float* out = (float*)d_out;

  float* w = (float*)d_ws;
  float* mpart  = w;                        // 2*432*8192 = 7,077,888 f
  float* mpart2 = mpart + 7077888;          // 2*8*8192
  float* separt = mpart2 + 131072;          // 2*432*64
  float* msum   = separt + 55296;           // 2*8192
  float* sesum  = msum + 16384;             // 128
  float* g32    = sesum + 128;              // 2*8192
  f16*   g16f   = (f16*)(g32 + 16384);      // 16,384 f16
  f16*   av_g   = g16f + 16384;             // 2*L*64 f16 = 14,155,776
  float* cpart  = (float*)(av_g + 14155776);// 2*216*4096 = 1,769,472 f
  float* mupart = cpart + 1769472;          // 2*216*64
  float* csum   = mupart + 27648;           // 2*4096
  float* musum  = csum + 8192;              // 128
  float* mr     = musum + 128;              // 512

  p1_proj_m<<<dim3(432, 2), 256, 0, stream>>>(x, WB, bB, WV, bV, av_g, mpart, separt);
  p2a<<<dim3(257, 2), 256, 0, stream>>>(mpart, separt, mpart2, sesum);
  p2a2<<<dim3(32, 2), 256, 0, stream>>>(mpart2, msum);
  p2b<<<dim3(32, 2), 256, 0, stream>>>(WA, bA, msum, sesum, g32, g16f);
  p3_cov<<<dim3(216, 2), 256, 0, stream>>>(av_g, cpart, mupart);
  p4a<<<dim3(65, 2), 256, 0, stream>>>(cpart, mupart, csum, musum);
  p4b<<<dim3(4, 2), 256, 0, stream>>>(csum, musum, g32, mr);
  p5_z<<<dim3(432, 2), 256, 0, stream>>>(av_g, g16f, mr, out);
}

// Round 12
// 144.132 us; speedup vs baseline: 1.1903x; 1.0352x over previous
//
#include <hip/hip_runtime.h>

#define LTOT 110592   // 48*48*48
#define EPSV 1e-5f

typedef _Float16 f16;
typedef __attribute__((ext_vector_type(4))) _Float16 f16x4;
typedef __attribute__((ext_vector_type(8))) _Float16 f16x8;
typedef __attribute__((ext_vector_type(4))) float f32x4;

#define MFMA16(a, b, c) __builtin_amdgcn_mfma_f32_16x16x32_f16(a, b, c, 0, 0, 0)
// XC swizzle: depends on both low and mid bits of c so that simultaneous
// writers (c strided by 8) AND simultaneous readers (c contiguous 16) spread.
#define SWC(c) ((((c) ^ ((c) >> 3)) & 7) << 3)

__device__ __forceinline__ f16x8 ld_w8(const float* p) {
  const float4 a = *(const float4*)p;
  const float4 b = *(const float4*)(p + 4);
  f16x8 f;
  f[0] = (f16)a.x; f[1] = (f16)a.y; f[2] = (f16)a.z; f[3] = (f16)a.w;
  f[4] = (f16)b.x; f[5] = (f16)b.y; f[6] = (f16)b.z; f[7] = (f16)b.w;
  return f;
}

// ============ P1: BmT,V proj (MFMA); e->EL; av-softmax->av_g; Mt += EL@XC ====
// grid (432, B), 4 tiles of 64 cols. Single X read/tile + reg prefetch (T14).
// LDS padded to 54.7KB -> exactly 2 blocks/CU (r6/r10: 3 blocks thrashes L2).
// Frozen: occupancy/barrier/drain levers all tested neutral-or-negative.
__global__ __launch_bounds__(256, 2) void p1_proj_m(
    const float* __restrict__ x,
    const float* __restrict__ WB_, const float* __restrict__ bB_,
    const float* __restrict__ WV_, const float* __restrict__ bV_,
    f16* __restrict__ av_g, float* __restrict__ mpart, float* __restrict__ separt)
{
  __shared__ __align__(16) f16 XT[64 * 128 + 2240];  // [l][c^((l&7)<<3)] (+pad)
  __shared__ __align__(16) f16 XC[128 * 64];  // [c][l^SWC(c)]
  __shared__ __align__(16) f16 EL[64 * 64];   // [n][l^((n&7)<<3)]
  __shared__ __align__(16) f16 AVT[64 * 64];  // [l][n^((l&7)<<3)] (unscaled exp)
  __shared__ float colp[4][64];
  const int tid = threadIdx.x, b = blockIdx.y, blk = blockIdx.x;
  const int ln = tid & 63, w = tid >> 6, g = ln >> 4;

  // W fragments (rows n = w*16 + (ln&15))
  const int nB = w * 16 + (ln & 15);
  f16x8 wbf[4], wvf[4];
  #pragma unroll
  for (int ks = 0; ks < 4; ++ks) {
    wbf[ks] = ld_w8(&WB_[nB * 128 + ks * 32 + g * 8]);
    wvf[ks] = ld_w8(&WV_[nB * 128 + ks * 32 + g * 8]);
  }
  const float sB = bB_[nB];
  float biasV[4];
  #pragma unroll
  for (int r = 0; r < 4; ++r) biasV[r] = bV_[w * 16 + g * 4 + r];

  f32x4 macc[8];
  #pragma unroll
  for (int i = 0; i < 8; ++i) macc[i] = (f32x4){0.f, 0.f, 0.f, 0.f};
  float se = 0.f;

  // staging thread map: c = co*8+j (j=0..7), l = LQ*4+i (i=0..3)
  const int co = tid & 15, LQ = tid >> 4;
  const size_t xb = (size_t)b * 128 * LTOT;

  float4 xr[8];
  {  // prologue: load tile 0
    const int l0 = blk * 256;
    #pragma unroll
    for (int j = 0; j < 8; ++j)
      xr[j] = *(const float4*)&x[xb + (size_t)(co * 8 + j) * LTOT + l0 + LQ * 4];
  }

  for (int t = 0; t < 4; ++t) {
    const int l0 = (blk * 4 + t) * 64;
    __syncthreads();   // prev tile's M-MFMA done reading XC
    // ---- stage from regs: XT [l][c] (4x f16x8) ----
    #pragma unroll
    for (int i = 0; i < 4; ++i) {
      const int l = LQ * 4 + i;
      f16x8 v;
      #pragma unroll
      for (int j = 0; j < 8; ++j) v[j] = (f16)(((const float*)&xr[j])[i]);
      *(f16x8*)&XT[l * 128 + ((co * 8) ^ ((l & 7) << 3))] = v;
    }
    // ---- stage from regs: XC [c][l] (8x f16x4, SWC swizzle) ----
    #pragma unroll
    for (int j = 0; j < 8; ++j) {
      const int c = co * 8 + j;
      f16x4 q;
      q[0] = (f16)xr[j].x; q[1] = (f16)xr[j].y;
      q[2] = (f16)xr[j].z; q[3] = (f16)xr[j].w;
      *(f16x4*)&XC[c * 64 + ((LQ * 4) ^ SWC(c))] = q;
    }
    __syncthreads();   // stage visible
    // ---- prefetch tile t+1 into regs: in flight across proj+exp ----
    if (t < 3) {
      const int l0n = l0 + 64;
      #pragma unroll
      for (int j = 0; j < 8; ++j)
        xr[j] = *(const float4*)&x[xb + (size_t)(co * 8 + j) * LTOT + l0n + LQ * 4];
    }
    // ---- proj: BmT (A=XT,B=WB) and V (A=WV,B=XT) share XT frags ----
    f32x4 aB[4], aV[4];
    #pragma unroll
    for (int lt = 0; lt < 4; ++lt) {
      aB[lt] = (f32x4){0.f, 0.f, 0.f, 0.f};
      aV[lt] = (f32x4){0.f, 0.f, 0.f, 0.f};
      const int l = lt * 16 + (ln & 15);
      #pragma unroll
      for (int ks = 0; ks < 4; ++ks) {
        const f16x8 xf = *(const f16x8*)&XT[l * 128 + (((ks * 4 + g) * 8) ^ ((l & 7) << 3))];
        aB[lt] = MFMA16(xf, wbf[ks], aB[lt]);
        aV[lt] = MFMA16(wvf[ks], xf, aV[lt]);
      }
    }
    // ---- e = exp(BmT + bias) -> EL (f16x4), sumexp ----
    #pragma unroll
    for (int lt = 0; lt < 4; ++lt) {
      f16x4 ev4;
      #pragma unroll
      for (int r = 0; r < 4; ++r) {
        const float e = __expf(aB[lt][r] + sB);
        se += e;
        ev4[r] = (f16)e;
      }
      const int lq = lt * 16 + g * 4;
      *(f16x4*)&EL[nB * 64 + (lq ^ ((nB & 7) << 3))] = ev4;
    }
    // ---- ev = exp(V + bias) -> AVT (unscaled), column-sum partials ----
    float cs[4];
    #pragma unroll
    for (int ct = 0; ct < 4; ++ct) {
      f16x4 av4;
      float s = 0.f;
      #pragma unroll
      for (int r = 0; r < 4; ++r) {
        const float e = __expf(aV[ct][r] + biasV[r]);
        s += e;
        av4[r] = (f16)e;
      }
      cs[ct] = s;
      const int l = ct * 16 + (ln & 15);
      *(f16x4*)&AVT[l * 64 + ((w * 16 + g * 4) ^ ((l & 7) << 3))] = av4;
    }
    #pragma unroll
    for (int ct = 0; ct < 4; ++ct) {
      cs[ct] += __shfl_xor(cs[ct], 16);
      cs[ct] += __shfl_xor(cs[ct], 32);
    }
    {
      const float v = (g == 0) ? cs[0] : (g == 1) ? cs[1] : (g == 2) ? cs[2] : cs[3];
      colp[w][g * 16 + (ln & 15)] = v;
    }
    __syncthreads();
    // ---- scale + store av tile to global [l][n] ----
    {
      const int l = tid >> 2, q = tid & 3;
      const float rs = 1.f / (colp[0][l] + colp[1][l] + colp[2][l] + colp[3][l]);
      f16x8 a0 = *(const f16x8*)&AVT[l * 64 + ((q * 16) ^ ((l & 7) << 3))];
      f16x8 a1 = *(const f16x8*)&AVT[l * 64 + ((q * 16 + 8) ^ ((l & 7) << 3))];
      #pragma unroll
      for (int j = 0; j < 8; ++j) {
        a0[j] = (f16)((float)a0[j] * rs);
        a1[j] = (f16)((float)a1[j] * rs);
      }
      f16* gp = av_g + ((size_t)b * LTOT + l0 + l) * 64 + q * 16;
      *(f16x8*)&gp[0] = a0;
      *(f16x8*)&gp[8] = a1;
    }
    // ---- Mt[n][c] += EL(A) @ XC(B), K=64 ----
    {
      f16x8 el[2];
      #pragma unroll
      for (int ks = 0; ks < 2; ++ks)
        el[ks] = *(const f16x8*)&EL[nB * 64 + ((ks * 32 + g * 8) ^ ((nB & 7) << 3))];
      #pragma unroll
      for (int cblk = 0; cblk < 8; ++cblk) {
        const int c = cblk * 16 + (ln & 15);
        #pragma unroll
        for (int ks = 0; ks < 2; ++ks) {
          const f16x8 xcf = *(const f16x8*)&XC[c * 64 + ((ks * 32 + g * 8) ^ SWC(c))];
          macc[cblk] = MFMA16(el[ks], xcf, macc[cblk]);
        }
      }
    }
  }
  // ---- write Mt partial [n][c] + sumexp partial ----
  float* mp = mpart + (size_t)(b * 432 + blk) * 8192;
  #pragma unroll
  for (int cblk = 0; cblk < 8; ++cblk)
    #pragma unroll
    for (int r = 0; r < 4; ++r)
      mp[(w * 16 + g * 4 + r) * 128 + cblk * 16 + (ln & 15)] = macc[cblk][r];
  se += __shfl_xor(se, 16);
  se += __shfl_xor(se, 32);
  if (ln < 16) separt[(size_t)(b * 432 + blk) * 64 + w * 16 + ln] = se;
}

// ============ P2a: Mt partials 432 -> 8 segs; sumexp 432 -> 1 ================
__global__ void p2a(const float* __restrict__ mpart, const float* __restrict__ separt,
                    float* __restrict__ mpart2, float* __restrict__ sesum)
{
  const int b = blockIdx.y, bx = blockIdx.x, tid = threadIdx.x;
  if (bx < 256) {
    const int seg = bx >> 5, chunk = bx & 31;
    const int idx = chunk * 256 + tid;
    float s = 0.f;
    #pragma unroll 4
    for (int j = 0; j < 54; ++j)
      s += mpart[(size_t)(b * 432 + seg * 54 + j) * 8192 + idx];
    mpart2[(size_t)(b * 8 + seg) * 8192 + idx] = s;
  } else if (tid < 64) {
    float s = 0.f;
    #pragma unroll 4
    for (int k = 0; k < 432; ++k) s += separt[(size_t)(b * 432 + k) * 64 + tid];
    sesum[b * 64 + tid] = s;
  }
}

// ============ P2a2: 8 segs -> msum [n][c] ====================================
__global__ void p2a2(const float* __restrict__ mpart2, float* __restrict__ msum)
{
  const int b = blockIdx.y;
  const int idx = blockIdx.x * 256 + threadIdx.x;
  float s = 0.f;
  #pragma unroll
  for (int k = 0; k < 8; ++k) s += mpart2[(size_t)(b * 8 + k) * 8192 + idx];
  msum[(size_t)b * 8192 + idx] = s;
}

// ============ P2b: G[m,n] = (WA@M)/sesum + bA; f32 [m][n] + swizzled f16 =====
__global__ void p2b(const float* __restrict__ WA_, const float* __restrict__ bA_,
                    const float* __restrict__ msum, const float* __restrict__ sesum,
                    float* __restrict__ g32, f16* __restrict__ g16)
{
  const int b = blockIdx.y;
  const int idx = blockIdx.x * 256 + threadIdx.x;
  const int m = idx >> 6, n = idx & 63;
  float s = 0.f;
  #pragma unroll 4
  for (int c = 0; c < 128; ++c) s += WA_[m * 128 + c] * msum[(size_t)b * 8192 + n * 128 + c];
  const float gv = s / sesum[b * 64 + n] + bA_[m];
  g32[(size_t)b * 8192 + m * 64 + n] = gv;
  g16[(size_t)b * 8192 + m * 64 + (n ^ ((m & 7) << 3))] = (f16)gv;
}

// ============ P3: C = av@av^T, mu = row-sums (reads av_g) ====================
// grid (216, B), 8 tiles each.
__global__ __launch_bounds__(256, 2) void p3_cov(
    const f16* __restrict__ av_g, float* __restrict__ cpart, float* __restrict__ mupart)
{
  __shared__ __align__(16) f16 AV[64 * 64];  // [n][l^((n&7)<<3)]
  const int tid = threadIdx.x, b = blockIdx.y, blk = blockIdx.x;
  const int ln = tid & 63, w = tid >> 6, g = ln >> 4;
  const int nq4 = (tid & 15) * 4, lq4 = (tid >> 4) * 4;  // stage: 4l x 4n
  const int nmu = tid >> 2, qmu = tid & 3;

  f32x4 cacc[4];
  #pragma unroll
  for (int j = 0; j < 4; ++j) cacc[j] = (f32x4){0.f, 0.f, 0.f, 0.f};
  float muacc = 0.f;

  for (int t = 0; t < 8; ++t) {
    const int l0 = (blk * 8 + t) * 64;
    __syncthreads();
    {  // stage: read [l][n] quads, transpose in regs, write [n][l] quads
      f16x4 rd[4];
      #pragma unroll
      for (int i = 0; i < 4; ++i)
        rd[i] = *(const f16x4*)&av_g[((size_t)b * LTOT + l0 + lq4 + i) * 64 + nq4];
      #pragma unroll
      for (int j = 0; j < 4; ++j) {
        const int n = nq4 + j;
        f16x4 wr;
        #pragma unroll
        for (int i = 0; i < 4; ++i) wr[i] = rd[i][j];
        *(f16x4*)&AV[n * 64 + (lq4 ^ ((n & 7) << 3))] = wr;
      }
    }
    __syncthreads();
    {  // mu partial: row sums
      const f16x8 a0 = *(const f16x8*)&AV[nmu * 64 + ((qmu * 16) ^ ((nmu & 7) << 3))];
      const f16x8 a1 = *(const f16x8*)&AV[nmu * 64 + ((qmu * 16 + 8) ^ ((nmu & 7) << 3))];
      #pragma unroll
      for (int j = 0; j < 8; ++j) muacc += (float)a0[j] + (float)a1[j];
    }
    // C MFMA: wave w owns rows n = w*16..+16
    const int nA = w * 16 + (ln & 15);
    f16x8 caf[2];
    #pragma unroll
    for (int ks = 0; ks < 2; ++ks)
      caf[ks] = *(const f16x8*)&AV[nA * 64 + ((ks * 32 + g * 8) ^ ((nA & 7) << 3))];
    #pragma unroll
    for (int nct = 0; nct < 4; ++nct) {
      const int nb = nct * 16 + (ln & 15);
      #pragma unroll
      for (int ks = 0; ks < 2; ++ks) {
        const f16x8 cbf = *(const f16x8*)&AV[nb * 64 + ((ks * 32 + g * 8) ^ ((nb & 7) << 3))];
        cacc[nct] = MFMA16(caf[ks], cbf, cacc[nct]);
      }
    }
  }
  float* cp = cpart + (size_t)(b * 216 + blk) * 4096;
  #pragma unroll
  for (int nct = 0; nct < 4; ++nct)
    #pragma unroll
    for (int r = 0; r < 4; ++r)
      cp[(w * 16 + g * 4 + r) * 64 + nct * 16 + (ln & 15)] = cacc[nct][r];
  muacc += __shfl_xor(muacc, 1);
  muacc += __shfl_xor(muacc, 2);
  if (qmu == 0) mupart[(size_t)(b * 216 + blk) * 64 + nmu] = muacc;
}

// ============ P4a: reduce C partials + mu partials ===========================
__global__ void p4a(const float* __restrict__ cpart, const float* __restrict__ mupart,
                    float* __restrict__ csum, float* __restrict__ musum)
{
  const int b = blockIdx.y, bx = blockIdx.x, tid = threadIdx.x;
  if (bx < 64) {
    const int idx = bx * 64 + (tid >> 2), q = tid & 3;
    float s = 0.f;
    for (int k = q; k < 216; k += 4) s += cpart[(size_t)(b * 216 + k) * 4096 + idx];
    s += __shfl_xor(s, 1);
    s += __shfl_xor(s, 2);
    if (q == 0) csum[(size_t)b * 4096 + idx] = s;
  } else if (tid < 64) {
    float s = 0.f;
    for (int k = 0; k < 216; ++k) s += mupart[(size_t)(b * 216 + k) * 64 + tid];
    musum[b * 64 + tid] = s;
  }
}

// ============ P4b: mean = G@mu/L; E[Z^2] = (G C G^T)_mm / L -> mean,rsig =====
__global__ void p4b(const float* __restrict__ csum, const float* __restrict__ musum,
                    const float* __restrict__ g32, float* __restrict__ mr)
{
  __shared__ __align__(16) float CL[4096];
  __shared__ __align__(16) float GLs[32 * 68];
  __shared__ float MUL[64];
  const int tid = threadIdx.x, b = blockIdx.y, bx = blockIdx.x;
  #pragma unroll
  for (int k = 0; k < 16; ++k) CL[k * 256 + tid] = csum[(size_t)b * 4096 + k * 256 + tid];
  #pragma unroll
  for (int k = 0; k < 8; ++k) {
    const int idx = k * 256 + tid;
    const int m_ = idx >> 6, n_ = idx & 63;
    GLs[m_ * 68 + n_] = g32[(size_t)b * 8192 + (bx * 32 + m_) * 64 + n_];
  }
  if (tid < 64) MUL[tid] = musum[b * 64 + tid];
  __syncthreads();
  const int mrow = (tid >> 3) * 68, oct = tid & 7;
  float q = 0.f;
  #pragma unroll
  for (int q4 = 0; q4 < 2; ++q4) {
    const int npb = oct * 8 + q4 * 4;
    float t0 = 0.f, t1 = 0.f, t2 = 0.f, t3 = 0.f;
    #pragma unroll 8
    for (int n = 0; n < 64; ++n) {
      const float4 cv = *(const float4*)&CL[n * 64 + npb];
      const float gv = GLs[mrow + n];
      t0 += gv * cv.x; t1 += gv * cv.y; t2 += gv * cv.z; t3 += gv * cv.w;
    }
    const float4 gq = *(const float4*)&GLs[mrow + npb];
    q += t0 * gq.x + t1 * gq.y + t2 * gq.z + t3 * gq.w;
  }
  q += __shfl_xor(q, 1); q += __shfl_xor(q, 2); q += __shfl_xor(q, 4);
  if (oct == 0) {
    float meanq = 0.f;
    #pragma unroll 8
    for (int n = 0; n < 64; ++n) meanq += GLs[mrow + n] * MUL[n];
    const int m = bx * 32 + (tid >> 3);
    const float mean = meanq / (float)LTOT;
    const float var = fmaxf(q / (float)LTOT - mean * mean, 0.f);
    mr[(b * 128 + m) * 2] = mean;
    mr[(b * 128 + m) * 2 + 1] = rsqrtf(var + EPSV);
  }
}

// ============ P5: Z = G@av (MFMA), LDS-free, wave-partitioned by l ===========
// grid (432, B), 4 tiles. Wave w owns l = w*16+(ln&15) of each 64-tile and
// computes ALL 128 m -> disjoint av reads across waves (28MB total, no dup),
// zero barriers, zero LDS.
__global__ __launch_bounds__(256, 2) void p5_z(
    const f16* __restrict__ av_g, const f16* __restrict__ g16,
    const float* __restrict__ mr, float* __restrict__ out)
{
  const int tid = threadIdx.x, b = blockIdx.y, blk = blockIdx.x;
  const int ln = tid & 63, w = tid >> 6, g = ln >> 4;

  // G fragments for ALL m (8 mct of 16 rows)
  f16x8 gf[8][2];
  float2 nrm[8][4];  // (mean, rsig) per (mct, r)
  #pragma unroll
  for (int mct = 0; mct < 8; ++mct) {
    const int mA = mct * 16 + (ln & 15);
    #pragma unroll
    for (int ks = 0; ks < 2; ++ks)
      gf[mct][ks] = *(const f16x8*)&g16[(size_t)b * 8192 + mA * 64 +
                                        (((ks * 4 + g) * 8) ^ ((mA & 7) << 3))];
    #pragma unroll
    for (int r = 0; r < 4; ++r) {
      const int m = mct * 16 + g * 4 + r;
      nrm[mct][r] = *(const float2*)&mr[(b * 128 + m) * 2];
    }
  }

  const int l = w * 16 + (ln & 15);  // this thread's l within each tile
  #pragma unroll
  for (int t = 0; t < 4; ++t) {
    const int l0 = (blk * 4 + t) * 64;
    const f16* ap = av_g + ((size_t)b * LTOT + l0 + l) * 64;
    f16x8 avf[2];
    #pragma unroll
    for (int ks = 0; ks < 2; ++ks)
      avf[ks] = *(const f16x8*)&ap[(ks * 4 + g) * 8];
    #pragma unroll
    for (int mct = 0; mct < 8; ++mct) {
      f32x4 z = {0.f, 0.f, 0.f, 0.f};
      #pragma unroll
      for (int ks = 0; ks < 2; ++ks) z = MFMA16(gf[mct][ks], avf[ks], z);
      #pragma unroll
      for (int r = 0; r < 4; ++r) {
        const int m = mct * 16 + g * 4 + r;
        out[(size_t)(b * 128 + m) * LTOT + l0 + l] =
            (z[r] - nrm[mct][r].x) * nrm[mct][r].y;
      }
    }
  }
}

extern "C" void kernel_launch(void* const* d_in, const int* in_sizes, int n_in,
                              void* d_out, int out_size, void* d_ws, size_t ws_size,
                              hipStream_t stream)
{
  const float* x  = (const float*)d_in[0];
  const float* WA = (const float*)d_in[1];
  const float* bA = (const float*)d_in[2];
  const float* WB = (const float*)d_in[3];
  const float* bB = (const float*)d_in[4];
  const float* WV = (const float*)d_in[5];
  const float* bV = (const float*)d_in[6];
  float* out = (float*)d_out;

  float* w = (float*)d_ws;
  float* mpart  = w;                        // 2*432*8192 = 7,077,888 f
  float* mpart2 = mpart + 7077888;          // 2*8*8192
  float* separt = mpart2 + 131072;          // 2*432*64
  float* msum   = separt + 55296;           // 2*8192
  float* sesum  = msum + 16384;             // 128
  float* g32    = sesum + 128;              // 2*8192
  f16*   g16f   = (f16*)(g32 + 16384);      // 16,384 f16
  f16*   av_g   = g16f + 16384;             // 2*L*64 f16 = 14,155,776
  float* cpart  = (float*)(av_g + 14155776);// 2*216*4096 = 1,769,472 f
  float* mupart = cpart + 1769472;          // 2*216*64
  float* csum   = mupart + 27648;           // 2*4096
  float* musum  = csum + 8192;              // 128
  float* mr     = musum + 128;              // 512

  p1_proj_m<<<dim3(432, 2), 256, 0, stream>>>(x, WB, bB, WV, bV, av_g, mpart, separt);
  p2a<<<dim3(257, 2), 256, 0, stream>>>(mpart, separt, mpart2, sesum);
  p2a2<<<dim3(32, 2), 256, 0, stream>>>(mpart2, msum);
  p2b<<<dim3(32, 2), 256, 0, stream>>>(WA, bA, msum, sesum, g32, g16f);
  p3_cov<<<dim3(216, 2), 256, 0, stream>>>(av_g, cpart, mupart);
  p4a<<<dim3(65, 2), 256, 0, stream>>>(cpart, mupart, csum, musum);
  p4b<<<dim3(4, 2), 256, 0, stream>>>(csum, musum, g32, mr);
  p5_z<<<dim3(432, 2), 256, 0, stream>>>(av_g, g16f, mr, out);
}

// Round 13
// 138.834 us; speedup vs baseline: 1.2357x; 1.0382x over previous
//
#include <hip/hip_runtime.h>

#define LTOT 110592   // 48*48*48
#define EPSV 1e-5f

typedef _Float16 f16;
typedef __attribute__((ext_vector_type(4))) _Float16 f16x4;
typedef __attribute__((ext_vector_type(8))) _Float16 f16x8;
typedef __attribute__((ext_vector_type(4))) float f32x4;

#define MFMA16(a, b, c) __builtin_amdgcn_mfma_f32_16x16x32_f16(a, b, c, 0, 0, 0)
// XC swizzle: depends on both low and mid bits of c so that simultaneous
// writers AND simultaneous readers spread across banks.
#define SWC(c) ((((c) ^ ((c) >> 3)) & 7) << 3)

__device__ __forceinline__ f16x8 ld_w8(const float* p) {
  const float4 a = *(const float4*)p;
  const float4 b = *(const float4*)(p + 4);
  f16x8 f;
  f[0] = (f16)a.x; f[1] = (f16)a.y; f[2] = (f16)a.z; f[3] = (f16)a.w;
  f[4] = (f16)b.x; f[5] = (f16)b.y; f[6] = (f16)b.z; f[7] = (f16)b.w;
  return f;
}

// ============ P1: BmT,V proj (MFMA); e->EL; av-softmax->av_g; Mt += EL@XC ====
// grid (432, B), 4 tiles of 64 cols. Single X read/tile + reg prefetch (T14).
// LDS padded to 54.7KB -> exactly 2 blocks/CU.
// r12 change: staging map swapped (co=tid>>4, LQ=tid&15) so each global load
// instruction touches 4 rows x 256B contiguous instead of 16 rows x 64B —
// attacks the measured 1.7 TB/s effective-HBM plateau.
__global__ __launch_bounds__(256, 2) void p1_proj_m(
    const float* __restrict__ x,
    const float* __restrict__ WB_, const float* __restrict__ bB_,
    const float* __restrict__ WV_, const float* __restrict__ bV_,
    f16* __restrict__ av_g, float* __restrict__ mpart, float* __restrict__ separt)
{
  __shared__ __align__(16) f16 XT[64 * 128 + 2240];  // [l][c^((l&7)<<3)] (+pad)
  __shared__ __align__(16) f16 XC[128 * 64];  // [c][l^SWC(c)]
  __shared__ __align__(16) f16 EL[64 * 64];   // [n][l^((n&7)<<3)]
  __shared__ __align__(16) f16 AVT[64 * 64];  // [l][n^((l&7)<<3)] (unscaled exp)
  __shared__ float colp[4][64];
  const int tid = threadIdx.x, b = blockIdx.y, blk = blockIdx.x;
  const int ln = tid & 63, w = tid >> 6, g = ln >> 4;

  // W fragments (rows n = w*16 + (ln&15))
  const int nB = w * 16 + (ln & 15);
  f16x8 wbf[4], wvf[4];
  #pragma unroll
  for (int ks = 0; ks < 4; ++ks) {
    wbf[ks] = ld_w8(&WB_[nB * 128 + ks * 32 + g * 8]);
    wvf[ks] = ld_w8(&WV_[nB * 128 + ks * 32 + g * 8]);
  }
  const float sB = bB_[nB];
  float biasV[4];
  #pragma unroll
  for (int r = 0; r < 4; ++r) biasV[r] = bV_[w * 16 + g * 4 + r];

  f32x4 macc[8];
  #pragma unroll
  for (int i = 0; i < 8; ++i) macc[i] = (f32x4){0.f, 0.f, 0.f, 0.f};
  float se = 0.f;

  // staging thread map (SWAPPED vs r7): c = co*8+j, l = LQ*4+i.
  // Within a wave: co spans 4 values, LQ spans 16 -> per load instruction
  // 4 rows x 256B contiguous (was 16 rows x 64B).
  const int co = tid >> 4, LQ = tid & 15;
  const size_t xb = (size_t)b * 128 * LTOT;

  float4 xr[8];
  {  // prologue: load tile 0
    const int l0 = blk * 256;
    #pragma unroll
    for (int j = 0; j < 8; ++j)
      xr[j] = *(const float4*)&x[xb + (size_t)(co * 8 + j) * LTOT + l0 + LQ * 4];
  }

  for (int t = 0; t < 4; ++t) {
    const int l0 = (blk * 4 + t) * 64;
    __syncthreads();   // prev tile's M-MFMA done reading XC
    // ---- stage from regs: XT [l][c] (4x f16x8) ----
    #pragma unroll
    for (int i = 0; i < 4; ++i) {
      const int l = LQ * 4 + i;
      f16x8 v;
      #pragma unroll
      for (int j = 0; j < 8; ++j) v[j] = (f16)(((const float*)&xr[j])[i]);
      *(f16x8*)&XT[l * 128 + ((co * 8) ^ ((l & 7) << 3))] = v;
    }
    // ---- stage from regs: XC [c][l] (8x f16x4, SWC swizzle) ----
    #pragma unroll
    for (int j = 0; j < 8; ++j) {
      const int c = co * 8 + j;
      f16x4 q;
      q[0] = (f16)xr[j].x; q[1] = (f16)xr[j].y;
      q[2] = (f16)xr[j].z; q[3] = (f16)xr[j].w;
      *(f16x4*)&XC[c * 64 + ((LQ * 4) ^ SWC(c))] = q;
    }
    __syncthreads();   // stage visible
    // ---- prefetch tile t+1 into regs: in flight across proj+exp ----
    if (t < 3) {
      const int l0n = l0 + 64;
      #pragma unroll
      for (int j = 0; j < 8; ++j)
        xr[j] = *(const float4*)&x[xb + (size_t)(co * 8 + j) * LTOT + l0n + LQ * 4];
    }
    // ---- proj: BmT (A=XT,B=WB) and V (A=WV,B=XT) share XT frags ----
    f32x4 aB[4], aV[4];
    #pragma unroll
    for (int lt = 0; lt < 4; ++lt) {
      aB[lt] = (f32x4){0.f, 0.f, 0.f, 0.f};
      aV[lt] = (f32x4){0.f, 0.f, 0.f, 0.f};
      const int l = lt * 16 + (ln & 15);
      #pragma unroll
      for (int ks = 0; ks < 4; ++ks) {
        const f16x8 xf = *(const f16x8*)&XT[l * 128 + (((ks * 4 + g) * 8) ^ ((l & 7) << 3))];
        aB[lt] = MFMA16(xf, wbf[ks], aB[lt]);
        aV[lt] = MFMA16(wvf[ks], xf, aV[lt]);
      }
    }
    // ---- e = exp(BmT + bias) -> EL (f16x4), sumexp ----
    #pragma unroll
    for (int lt = 0; lt < 4; ++lt) {
      f16x4 ev4;
      #pragma unroll
      for (int r = 0; r < 4; ++r) {
        const float e = __expf(aB[lt][r] + sB);
        se += e;
        ev4[r] = (f16)e;
      }
      const int lq = lt * 16 + g * 4;
      *(f16x4*)&EL[nB * 64 + (lq ^ ((nB & 7) << 3))] = ev4;
    }
    // ---- ev = exp(V + bias) -> AVT (unscaled), column-sum partials ----
    float cs[4];
    #pragma unroll
    for (int ct = 0; ct < 4; ++ct) {
      f16x4 av4;
      float s = 0.f;
      #pragma unroll
      for (int r = 0; r < 4; ++r) {
        const float e = __expf(aV[ct][r] + biasV[r]);
        s += e;
        av4[r] = (f16)e;
      }
      cs[ct] = s;
      const int l = ct * 16 + (ln & 15);
      *(f16x4*)&AVT[l * 64 + ((w * 16 + g * 4) ^ ((l & 7) << 3))] = av4;
    }
    #pragma unroll
    for (int ct = 0; ct < 4; ++ct) {
      cs[ct] += __shfl_xor(cs[ct], 16);
      cs[ct] += __shfl_xor(cs[ct], 32);
    }
    {
      const float v = (g == 0) ? cs[0] : (g == 1) ? cs[1] : (g == 2) ? cs[2] : cs[3];
      colp[w][g * 16 + (ln & 15)] = v;
    }
    __syncthreads();
    // ---- scale + store av tile to global [l][n] ----
    {
      const int l = tid >> 2, q = tid & 3;
      const float rs = 1.f / (colp[0][l] + colp[1][l] + colp[2][l] + colp[3][l]);
      f16x8 a0 = *(const f16x8*)&AVT[l * 64 + ((q * 16) ^ ((l & 7) << 3))];
      f16x8 a1 = *(const f16x8*)&AVT[l * 64 + ((q * 16 + 8) ^ ((l & 7) << 3))];
      #pragma unroll
      for (int j = 0; j < 8; ++j) {
        a0[j] = (f16)((float)a0[j] * rs);
        a1[j] = (f16)((float)a1[j] * rs);
      }
      f16* gp = av_g + ((size_t)b * LTOT + l0 + l) * 64 + q * 16;
      *(f16x8*)&gp[0] = a0;
      *(f16x8*)&gp[8] = a1;
    }
    // ---- Mt[n][c] += EL(A) @ XC(B), K=64 ----
    {
      f16x8 el[2];
      #pragma unroll
      for (int ks = 0; ks < 2; ++ks)
        el[ks] = *(const f16x8*)&EL[nB * 64 + ((ks * 32 + g * 8) ^ ((nB & 7) << 3))];
      #pragma unroll
      for (int cblk = 0; cblk < 8; ++cblk) {
        const int c = cblk * 16 + (ln & 15);
        #pragma unroll
        for (int ks = 0; ks < 2; ++ks) {
          const f16x8 xcf = *(const f16x8*)&XC[c * 64 + ((ks * 32 + g * 8) ^ SWC(c))];
          macc[cblk] = MFMA16(el[ks], xcf, macc[cblk]);
        }
      }
    }
  }
  // ---- write Mt partial [n][c] + sumexp partial ----
  float* mp = mpart + (size_t)(b * 432 + blk) * 8192;
  #pragma unroll
  for (int cblk = 0; cblk < 8; ++cblk)
    #pragma unroll
    for (int r = 0; r < 4; ++r)
      mp[(w * 16 + g * 4 + r) * 128 + cblk * 16 + (ln & 15)] = macc[cblk][r];
  se += __shfl_xor(se, 16);
  se += __shfl_xor(se, 32);
  if (ln < 16) separt[(size_t)(b * 432 + blk) * 64 + w * 16 + ln] = se;
}

// ============ P2a: Mt partials 432 -> 8 segs; sumexp 432 -> 1 ================
__global__ void p2a(const float* __restrict__ mpart, const float* __restrict__ separt,
                    float* __restrict__ mpart2, float* __restrict__ sesum)
{
  const int b = blockIdx.y, bx = blockIdx.x, tid = threadIdx.x;
  if (bx < 256) {
    const int seg = bx >> 5, chunk = bx & 31;
    const int idx = chunk * 256 + tid;
    float s = 0.f;
    #pragma unroll 4
    for (int j = 0; j < 54; ++j)
      s += mpart[(size_t)(b * 432 + seg * 54 + j) * 8192 + idx];
    mpart2[(size_t)(b * 8 + seg) * 8192 + idx] = s;
  } else if (tid < 64) {
    float s = 0.f;
    #pragma unroll 4
    for (int k = 0; k < 432; ++k) s += separt[(size_t)(b * 432 + k) * 64 + tid];
    sesum[b * 64 + tid] = s;
  }
}

// ============ P2a2: 8 segs -> msum [n][c] ====================================
__global__ void p2a2(const float* __restrict__ mpart2, float* __restrict__ msum)
{
  const int b = blockIdx.y;
  const int idx = blockIdx.x * 256 + threadIdx.x;
  float s = 0.f;
  #pragma unroll
  for (int k = 0; k < 8; ++k) s += mpart2[(size_t)(b * 8 + k) * 8192 + idx];
  msum[(size_t)b * 8192 + idx] = s;
}

// ============ P2b: G[m,n] = (WA@M)/sesum + bA; f32 [m][n] + swizzled f16 =====
__global__ void p2b(const float* __restrict__ WA_, const float* __restrict__ bA_,
                    const float* __restrict__ msum, const float* __restrict__ sesum,
                    float* __restrict__ g32, f16* __restrict__ g16)
{
  const int b = blockIdx.y;
  const int idx = blockIdx.x * 256 + threadIdx.x;
  const int m = idx >> 6, n = idx & 63;
  float s = 0.f;
  #pragma unroll 4
  for (int c = 0; c < 128; ++c) s += WA_[m * 128 + c] * msum[(size_t)b * 8192 + n * 128 + c];
  const float gv = s / sesum[b * 64 + n] + bA_[m];
  g32[(size_t)b * 8192 + m * 64 + n] = gv;
  g16[(size_t)b * 8192 + m * 64 + (n ^ ((m & 7) << 3))] = (f16)gv;
}

// ============ P3: C = av@av^T, mu = row-sums (reads av_g) ====================
// grid (216, B), 8 tiles each.
__global__ __launch_bounds__(256, 2) void p3_cov(
    const f16* __restrict__ av_g, float* __restrict__ cpart, float* __restrict__ mupart)
{
  __shared__ __align__(16) f16 AV[64 * 64];  // [n][l^((n&7)<<3)]
  const int tid = threadIdx.x, b = blockIdx.y, blk = blockIdx.x;
  const int ln = tid & 63, w = tid >> 6, g = ln >> 4;
  const int nq4 = (tid & 15) * 4, lq4 = (tid >> 4) * 4;  // stage: 4l x 4n
  const int nmu = tid >> 2, qmu = tid & 3;

  f32x4 cacc[4];
  #pragma unroll
  for (int j = 0; j < 4; ++j) cacc[j] = (f32x4){0.f, 0.f, 0.f, 0.f};
  float muacc = 0.f;

  for (int t = 0; t < 8; ++t) {
    const int l0 = (blk * 8 + t) * 64;
    __syncthreads();
    {  // stage: read [l][n] quads, transpose in regs, write [n][l] quads
      f16x4 rd[4];
      #pragma unroll
      for (int i = 0; i < 4; ++i)
        rd[i] = *(const f16x4*)&av_g[((size_t)b * LTOT + l0 + lq4 + i) * 64 + nq4];
      #pragma unroll
      for (int j = 0; j < 4; ++j) {
        const int n = nq4 + j;
        f16x4 wr;
        #pragma unroll
        for (int i = 0; i < 4; ++i) wr[i] = rd[i][j];
        *(f16x4*)&AV[n * 64 + (lq4 ^ ((n & 7) << 3))] = wr;
      }
    }
    __syncthreads();
    {  // mu partial: row sums
      const f16x8 a0 = *(const f16x8*)&AV[nmu * 64 + ((qmu * 16) ^ ((nmu & 7) << 3))];
      const f16x8 a1 = *(const f16x8*)&AV[nmu * 64 + ((qmu * 16 + 8) ^ ((nmu & 7) << 3))];
      #pragma unroll
      for (int j = 0; j < 8; ++j) muacc += (float)a0[j] + (float)a1[j];
    }
    // C MFMA: wave w owns rows n = w*16..+16
    const int nA = w * 16 + (ln & 15);
    f16x8 caf[2];
    #pragma unroll
    for (int ks = 0; ks < 2; ++ks)
      caf[ks] = *(const f16x8*)&AV[nA * 64 + ((ks * 32 + g * 8) ^ ((nA & 7) << 3))];
    #pragma unroll
    for (int nct = 0; nct < 4; ++nct) {
      const int nb = nct * 16 + (ln & 15);
      #pragma unroll
      for (int ks = 0; ks < 2; ++ks) {
        const f16x8 cbf = *(const f16x8*)&AV[nb * 64 + ((ks * 32 + g * 8) ^ ((nb & 7) << 3))];
        cacc[nct] = MFMA16(caf[ks], cbf, cacc[nct]);
      }
    }
  }
  float* cp = cpart + (size_t)(b * 216 + blk) * 4096;
  #pragma unroll
  for (int nct = 0; nct < 4; ++nct)
    #pragma unroll
    for (int r = 0; r < 4; ++r)
      cp[(w * 16 + g * 4 + r) * 64 + nct * 16 + (ln & 15)] = cacc[nct][r];
  muacc += __shfl_xor(muacc, 1);
  muacc += __shfl_xor(muacc, 2);
  if (qmu == 0) mupart[(size_t)(b * 216 + blk) * 64 + nmu] = muacc;
}

// ============ P4a: reduce C partials + mu partials ===========================
__global__ void p4a(const float* __restrict__ cpart, const float* __restrict__ mupart,
                    float* __restrict__ csum, float* __restrict__ musum)
{
  const int b = blockIdx.y, bx = blockIdx.x, tid = threadIdx.x;
  if (bx < 64) {
    const int idx = bx * 64 + (tid >> 2), q = tid & 3;
    float s = 0.f;
    for (int k = q; k < 216; k += 4) s += cpart[(size_t)(b * 216 + k) * 4096 + idx];
    s += __shfl_xor(s, 1);
    s += __shfl_xor(s, 2);
    if (q == 0) csum[(size_t)b * 4096 + idx] = s;
  } else if (tid < 64) {
    float s = 0.f;
    for (int k = 0; k < 216; ++k) s += mupart[(size_t)(b * 216 + k) * 64 + tid];
    musum[b * 64 + tid] = s;
  }
}

// ============ P4b: mean = G@mu/L; E[Z^2] = (G C G^T)_mm / L -> mean,rsig =====
__global__ void p4b(const float* __restrict__ csum, const float* __restrict__ musum,
                    const float* __restrict__ g32, float* __restrict__ mr)
{
  __shared__ __align__(16) float CL[4096];
  __shared__ __align__(16) float GLs[32 * 68];
  __shared__ float MUL[64];
  const int tid = threadIdx.x, b = blockIdx.y, bx = blockIdx.x;
  #pragma unroll
  for (int k = 0; k < 16; ++k) CL[k * 256 + tid] = csum[(size_t)b * 4096 + k * 256 + tid];
  #pragma unroll
  for (int k = 0; k < 8; ++k) {
    const int idx = k * 256 + tid;
    const int m_ = idx >> 6, n_ = idx & 63;
    GLs[m_ * 68 + n_] = g32[(size_t)b * 8192 + (bx * 32 + m_) * 64 + n_];
  }
  if (tid < 64) MUL[tid] = musum[b * 64 + tid];
  __syncthreads();
  const int mrow = (tid >> 3) * 68, oct = tid & 7;
  float q = 0.f;
  #pragma unroll
  for (int q4 = 0; q4 < 2; ++q4) {
    const int npb = oct * 8 + q4 * 4;
    float t0 = 0.f, t1 = 0.f, t2 = 0.f, t3 = 0.f;
    #pragma unroll 8
    for (int n = 0; n < 64; ++n) {
      const float4 cv = *(const float4*)&CL[n * 64 + npb];
      const float gv = GLs[mrow + n];
      t0 += gv * cv.x; t1 += gv * cv.y; t2 += gv * cv.z; t3 += gv * cv.w;
    }
    const float4 gq = *(const float4*)&GLs[mrow + npb];
    q += t0 * gq.x + t1 * gq.y + t2 * gq.z + t3 * gq.w;
  }
  q += __shfl_xor(q, 1); q += __shfl_xor(q, 2); q += __shfl_xor(q, 4);
  if (oct == 0) {
    float meanq = 0.f;
    #pragma unroll 8
    for (int n = 0; n < 64; ++n) meanq += GLs[mrow + n] * MUL[n];
    const int m = bx * 32 + (tid >> 3);
    const float mean = meanq / (float)LTOT;
    const float var = fmaxf(q / (float)LTOT - mean * mean, 0.f);
    mr[(b * 128 + m) * 2] = mean;
    mr[(b * 128 + m) * 2 + 1] = rsqrtf(var + EPSV);
  }
}

// ============ P5: Z = G@av (MFMA), write normalized ==========================
// grid (432, B), 4 tiles each (r7 LDS-staged version — best measured).
__global__ __launch_bounds__(256, 2) void p5_z(
    const f16* __restrict__ av_g, const f16* __restrict__ g16,
    const float* __restrict__ mr, float* __restrict__ out)
{
  __shared__ __align__(16) f16 AVT[64 * 64];  // [l][n^((l&7)<<3)]
  const int tid = threadIdx.x, b = blockIdx.y, blk = blockIdx.x;
  const int ln = tid & 63, w = tid >> 6, g = ln >> 4;
  const int lst = tid & 63, pst = tid >> 6;

  // G fragments: wave w owns m = w*32..+32 (2 mct of 16)
  f16x8 gf[2][2];
  float mean_[2][4], rsig_[2][4];
  #pragma unroll
  for (int mct = 0; mct < 2; ++mct) {
    const int mA = w * 32 + mct * 16 + (ln & 15);
    #pragma unroll
    for (int ks = 0; ks < 2; ++ks)
      gf[mct][ks] = *(const f16x8*)&g16[(size_t)b * 8192 + mA * 64 +
                                        (((ks * 4 + g) * 8) ^ ((mA & 7) << 3))];
    #pragma unroll
    for (int r = 0; r < 4; ++r) {
      const int m = w * 32 + mct * 16 + g * 4 + r;
      mean_[mct][r] = mr[(b * 128 + m) * 2];
      rsig_[mct][r] = mr[(b * 128 + m) * 2 + 1];
    }
  }

  for (int t = 0; t < 4; ++t) {
    const int l0 = (blk * 4 + t) * 64;
    __syncthreads();
    {  // stage av tile: straight vector copy with swizzle
      const f16* gp = av_g + ((size_t)b * LTOT + l0 + lst) * 64 + pst * 16;
      const f16x8 a0 = *(const f16x8*)&gp[0];
      const f16x8 a1 = *(const f16x8*)&gp[8];
      *(f16x8*)&AVT[lst * 64 + ((pst * 16) ^ ((lst & 7) << 3))] = a0;
      *(f16x8*)&AVT[lst * 64 + ((pst * 16 + 8) ^ ((lst & 7) << 3))] = a1;
    }
    __syncthreads();
    #pragma unroll
    for (int lt = 0; lt < 4; ++lt) {
      const int l = lt * 16 + (ln & 15);
      f16x8 avf[2];
      #pragma unroll
      for (int ks = 0; ks < 2; ++ks)
        avf[ks] = *(const f16x8*)&AVT[l * 64 + (((ks * 4 + g) * 8) ^ ((l & 7) << 3))];
      #pragma unroll
      for (int mct = 0; mct < 2; ++mct) {
        f32x4 z = {0.f, 0.f, 0.f, 0.f};
        #pragma unroll
        for (int ks = 0; ks < 2; ++ks) z = MFMA16(gf[mct][ks], avf[ks], z);
        #pragma unroll
        for (int r = 0; r < 4; ++r) {
          const int m = w * 32 + mct * 16 + g * 4 + r;
          out[(size_t)(b * 128 + m) * LTOT + l0 + l] =
              (z[r] - mean_[mct][r]) * rsig_[mct][r];
        }
      }
    }
  }
}

extern "C" void kernel_launch(void* const* d_in, const int* in_sizes, int n_in,
                              void* d_out, int out_size, void* d_ws, size_t ws_size,
                              hipStream_t stream)
{
  const float* x  = (const float*)d_in[0];
  const float* WA = (const float*)d_in[1];
  const float* bA = (const float*)d_in[2];
  const float* WB = (const float*)d_in[3];
  const float* bB = (const float*)d_in[4];
  const float* WV = (const float*)d_in[5];
  const float* bV = (const float*)d_in[6];
  float* out = (float*)d_out;

  float* w = (float*)d_ws;
  float* mpart  = w;                        // 2*432*8192 = 7,077,888 f
  float* mpart2 = mpart + 7077888;          // 2*8*8192
  float* separt = mpart2 + 131072;          // 2*432*64
  float* msum   = separt + 55296;           // 2*8192
  float* sesum  = msum + 16384;             // 128
  float* g32    = sesum + 128;              // 2*8192
  f16*   g16f   = (f16*)(g32 + 16384);      // 16,384 f16
  f16*   av_g   = g16f + 16384;             // 2*L*64 f16 = 14,155,776
  float* cpart  = (float*)(av_g + 14155776);// 2*216*4096 = 1,769,472 f
  float* mupart = cpart + 1769472;          // 2*216*64
  float* csum   = mupart + 27648;           // 2*4096
  float* musum  = csum + 8192;              // 128
  float* mr     = musum + 128;              // 512

  p1_proj_m<<<dim3(432, 2), 256, 0, stream>>>(x, WB, bB, WV, bV, av_g, mpart, separt);
  p2a<<<dim3(257, 2), 256, 0, stream>>>(mpart, separt, mpart2, sesum);
  p2a2<<<dim3(32, 2), 256, 0, stream>>>(mpart2, msum);
  p2b<<<dim3(32, 2), 256, 0, stream>>>(WA, bA, msum, sesum, g32, g16f);
  p3_cov<<<dim3(216, 2), 256, 0, stream>>>(av_g, cpart, mupart);
  p4a<<<dim3(65, 2), 256, 0, stream>>>(cpart, mupart, csum, musum);
  p4b<<<dim3(4, 2), 256, 0, stream>>>(csum, musum, g32, mr);
  p5_z<<<dim3(432, 2), 256, 0, stream>>>(av_g, g16f, mr, out);
}

// Round 14
// 123.741 us; speedup vs baseline: 1.3864x; 1.1220x over previous
//
#include <hip/hip_runtime.h>

#define LTOT 110592   // 48*48*48
#define EPSV 1e-5f

typedef _Float16 f16;
typedef __attribute__((ext_vector_type(4))) _Float16 f16x4;
typedef __attribute__((ext_vector_type(8))) _Float16 f16x8;
typedef __attribute__((ext_vector_type(4))) float f32x4;

#define MFMA16(a, b, c) __builtin_amdgcn_mfma_f32_16x16x32_f16(a, b, c, 0, 0, 0)
// XC swizzle: depends on both low and mid bits of c so that simultaneous
// writers AND simultaneous readers spread across banks.
#define SWC(c) ((((c) ^ ((c) >> 3)) & 7) << 3)

__device__ __forceinline__ f16x8 ld_w8(const float* p) {
  const float4 a = *(const float4*)p;
  const float4 b = *(const float4*)(p + 4);
  f16x8 f;
  f[0] = (f16)a.x; f[1] = (f16)a.y; f[2] = (f16)a.z; f[3] = (f16)a.w;
  f[4] = (f16)b.x; f[5] = (f16)b.y; f[6] = (f16)b.z; f[7] = (f16)b.w;
  return f;
}

// ============ P1: BmT,V proj (MFMA); e->EL; av-softmax->av_g; Mt += EL@XC ====
// grid (432, B), 4 tiles of 64 cols. Single X read/tile + reg prefetch (T14).
// LDS padded to 54.7KB -> exactly 2 blocks/CU.
// Staging map (r13-measured faster): co=tid>>4, LQ=tid&15 -> each global load
// instruction covers 4 rows x 256B contiguous (was 16 rows x 64B).
__global__ __launch_bounds__(256, 2) void p1_proj_m(
    const float* __restrict__ x,
    const float* __restrict__ WB_, const float* __restrict__ bB_,
    const float* __restrict__ WV_, const float* __restrict__ bV_,
    f16* __restrict__ av_g, float* __restrict__ mpart, float* __restrict__ separt)
{
  __shared__ __align__(16) f16 XT[64 * 128 + 2240];  // [l][c^((l&7)<<3)] (+pad)
  __shared__ __align__(16) f16 XC[128 * 64];  // [c][l^SWC(c)]
  __shared__ __align__(16) f16 EL[64 * 64];   // [n][l^((n&7)<<3)]
  __shared__ __align__(16) f16 AVT[64 * 64];  // [l][n^((l&7)<<3)] (unscaled exp)
  __shared__ float colp[4][64];
  const int tid = threadIdx.x, b = blockIdx.y, blk = blockIdx.x;
  const int ln = tid & 63, w = tid >> 6, g = ln >> 4;

  // W fragments (rows n = w*16 + (ln&15))
  const int nB = w * 16 + (ln & 15);
  f16x8 wbf[4], wvf[4];
  #pragma unroll
  for (int ks = 0; ks < 4; ++ks) {
    wbf[ks] = ld_w8(&WB_[nB * 128 + ks * 32 + g * 8]);
    wvf[ks] = ld_w8(&WV_[nB * 128 + ks * 32 + g * 8]);
  }
  const float sB = bB_[nB];
  float biasV[4];
  #pragma unroll
  for (int r = 0; r < 4; ++r) biasV[r] = bV_[w * 16 + g * 4 + r];

  f32x4 macc[8];
  #pragma unroll
  for (int i = 0; i < 8; ++i) macc[i] = (f32x4){0.f, 0.f, 0.f, 0.f};
  float se = 0.f;

  // staging thread map: c = co*8+j (j=0..7), l = LQ*4+i (i=0..3)
  const int co = tid >> 4, LQ = tid & 15;
  const size_t xb = (size_t)b * 128 * LTOT;

  float4 xr[8];
  {  // prologue: load tile 0
    const int l0 = blk * 256;
    #pragma unroll
    for (int j = 0; j < 8; ++j)
      xr[j] = *(const float4*)&x[xb + (size_t)(co * 8 + j) * LTOT + l0 + LQ * 4];
  }

  for (int t = 0; t < 4; ++t) {
    const int l0 = (blk * 4 + t) * 64;
    __syncthreads();   // prev tile's M-MFMA done reading XC
    // ---- stage from regs: XT [l][c] (4x f16x8) ----
    #pragma unroll
    for (int i = 0; i < 4; ++i) {
      const int l = LQ * 4 + i;
      f16x8 v;
      #pragma unroll
      for (int j = 0; j < 8; ++j) v[j] = (f16)(((const float*)&xr[j])[i]);
      *(f16x8*)&XT[l * 128 + ((co * 8) ^ ((l & 7) << 3))] = v;
    }
    // ---- stage from regs: XC [c][l] (8x f16x4, SWC swizzle) ----
    #pragma unroll
    for (int j = 0; j < 8; ++j) {
      const int c = co * 8 + j;
      f16x4 q;
      q[0] = (f16)xr[j].x; q[1] = (f16)xr[j].y;
      q[2] = (f16)xr[j].z; q[3] = (f16)xr[j].w;
      *(f16x4*)&XC[c * 64 + ((LQ * 4) ^ SWC(c))] = q;
    }
    __syncthreads();   // stage visible
    // ---- prefetch tile t+1 into regs: in flight across proj+exp ----
    if (t < 3) {
      const int l0n = l0 + 64;
      #pragma unroll
      for (int j = 0; j < 8; ++j)
        xr[j] = *(const float4*)&x[xb + (size_t)(co * 8 + j) * LTOT + l0n + LQ * 4];
    }
    // ---- proj: BmT (A=XT,B=WB) and V (A=WV,B=XT) share XT frags ----
    f32x4 aB[4], aV[4];
    #pragma unroll
    for (int lt = 0; lt < 4; ++lt) {
      aB[lt] = (f32x4){0.f, 0.f, 0.f, 0.f};
      aV[lt] = (f32x4){0.f, 0.f, 0.f, 0.f};
      const int l = lt * 16 + (ln & 15);
      #pragma unroll
      for (int ks = 0; ks < 4; ++ks) {
        const f16x8 xf = *(const f16x8*)&XT[l * 128 + (((ks * 4 + g) * 8) ^ ((l & 7) << 3))];
        aB[lt] = MFMA16(xf, wbf[ks], aB[lt]);
        aV[lt] = MFMA16(wvf[ks], xf, aV[lt]);
      }
    }
    // ---- e = exp(BmT + bias) -> EL (f16x4), sumexp ----
    #pragma unroll
    for (int lt = 0; lt < 4; ++lt) {
      f16x4 ev4;
      #pragma unroll
      for (int r = 0; r < 4; ++r) {
        const float e = __expf(aB[lt][r] + sB);
        se += e;
        ev4[r] = (f16)e;
      }
      const int lq = lt * 16 + g * 4;
      *(f16x4*)&EL[nB * 64 + (lq ^ ((nB & 7) << 3))] = ev4;
    }
    // ---- ev = exp(V + bias) -> AVT (unscaled), column-sum partials ----
    float cs[4];
    #pragma unroll
    for (int ct = 0; ct < 4; ++ct) {
      f16x4 av4;
      float s = 0.f;
      #pragma unroll
      for (int r = 0; r < 4; ++r) {
        const float e = __expf(aV[ct][r] + biasV[r]);
        s += e;
        av4[r] = (f16)e;
      }
      cs[ct] = s;
      const int l = ct * 16 + (ln & 15);
      *(f16x4*)&AVT[l * 64 + ((w * 16 + g * 4) ^ ((l & 7) << 3))] = av4;
    }
    #pragma unroll
    for (int ct = 0; ct < 4; ++ct) {
      cs[ct] += __shfl_xor(cs[ct], 16);
      cs[ct] += __shfl_xor(cs[ct], 32);
    }
    {
      const float v = (g == 0) ? cs[0] : (g == 1) ? cs[1] : (g == 2) ? cs[2] : cs[3];
      colp[w][g * 16 + (ln & 15)] = v;
    }
    __syncthreads();
    // ---- scale + store av tile to global [l][n] ----
    {
      const int l = tid >> 2, q = tid & 3;
      const float rs = 1.f / (colp[0][l] + colp[1][l] + colp[2][l] + colp[3][l]);
      f16x8 a0 = *(const f16x8*)&AVT[l * 64 + ((q * 16) ^ ((l & 7) << 3))];
      f16x8 a1 = *(const f16x8*)&AVT[l * 64 + ((q * 16 + 8) ^ ((l & 7) << 3))];
      #pragma unroll
      for (int j = 0; j < 8; ++j) {
        a0[j] = (f16)((float)a0[j] * rs);
        a1[j] = (f16)((float)a1[j] * rs);
      }
      f16* gp = av_g + ((size_t)b * LTOT + l0 + l) * 64 + q * 16;
      *(f16x8*)&gp[0] = a0;
      *(f16x8*)&gp[8] = a1;
    }
    // ---- Mt[n][c] += EL(A) @ XC(B), K=64 ----
    {
      f16x8 el[2];
      #pragma unroll
      for (int ks = 0; ks < 2; ++ks)
        el[ks] = *(const f16x8*)&EL[nB * 64 + ((ks * 32 + g * 8) ^ ((nB & 7) << 3))];
      #pragma unroll
      for (int cblk = 0; cblk < 8; ++cblk) {
        const int c = cblk * 16 + (ln & 15);
        #pragma unroll
        for (int ks = 0; ks < 2; ++ks) {
          const f16x8 xcf = *(const f16x8*)&XC[c * 64 + ((ks * 32 + g * 8) ^ SWC(c))];
          macc[cblk] = MFMA16(el[ks], xcf, macc[cblk]);
        }
      }
    }
  }
  // ---- write Mt partial [n][c] + sumexp partial ----
  float* mp = mpart + (size_t)(b * 432 + blk) * 8192;
  #pragma unroll
  for (int cblk = 0; cblk < 8; ++cblk)
    #pragma unroll
    for (int r = 0; r < 4; ++r)
      mp[(w * 16 + g * 4 + r) * 128 + cblk * 16 + (ln & 15)] = macc[cblk][r];
  se += __shfl_xor(se, 16);
  se += __shfl_xor(se, 32);
  if (ln < 16) separt[(size_t)(b * 432 + blk) * 64 + w * 16 + ln] = se;
}

// ============ P2a: Mt partials 432 -> 8 segs; sumexp 432 -> 1 ================
__global__ void p2a(const float* __restrict__ mpart, const float* __restrict__ separt,
                    float* __restrict__ mpart2, float* __restrict__ sesum)
{
  const int b = blockIdx.y, bx = blockIdx.x, tid = threadIdx.x;
  if (bx < 256) {
    const int seg = bx >> 5, chunk = bx & 31;
    const int idx = chunk * 256 + tid;
    float s = 0.f;
    for (int j = 0; j < 54; ++j)
      s += mpart[(size_t)(b * 432 + seg * 54 + j) * 8192 + idx];
    mpart2[(size_t)(b * 8 + seg) * 8192 + idx] = s;
  } else if (tid < 64) {
    float s = 0.f;
    for (int k = 0; k < 432; ++k) s += separt[(size_t)(b * 432 + k) * 64 + tid];
    sesum[b * 64 + tid] = s;
  }
}

// ============ P2a2: 8 segs -> msum [n][c] ====================================
__global__ void p2a2(const float* __restrict__ mpart2, float* __restrict__ msum)
{
  const int b = blockIdx.y;
  const int idx = blockIdx.x * 256 + threadIdx.x;
  float s = 0.f;
  #pragma unroll
  for (int k = 0; k < 8; ++k) s += mpart2[(size_t)(b * 8 + k) * 8192 + idx];
  msum[(size_t)b * 8192 + idx] = s;
}

// ============ P2b: G[m,n] = (WA@M)/sesum + bA; f32 [m][n] + swizzled f16 =====
__global__ void p2b(const float* __restrict__ WA_, const float* __restrict__ bA_,
                    const float* __restrict__ msum, const float* __restrict__ sesum,
                    float* __restrict__ g32, f16* __restrict__ g16)
{
  const int b = blockIdx.y;
  const int idx = blockIdx.x * 256 + threadIdx.x;
  const int m = idx >> 6, n = idx & 63;
  float s = 0.f;
  #pragma unroll 4
  for (int c = 0; c < 128; ++c) s += WA_[m * 128 + c] * msum[(size_t)b * 8192 + n * 128 + c];
  const float gv = s / sesum[b * 64 + n] + bA_[m];
  g32[(size_t)b * 8192 + m * 64 + n] = gv;
  g16[(size_t)b * 8192 + m * 64 + (n ^ ((m & 7) << 3))] = (f16)gv;
}

// ============ P3: C = av@av^T, mu = row-sums (reads av_g) ====================
// grid (216, B), 8 tiles each.
__global__ __launch_bounds__(256, 2) void p3_cov(
    const f16* __restrict__ av_g, float* __restrict__ cpart, float* __restrict__ mupart)
{
  __shared__ __align__(16) f16 AV[64 * 64];  // [n][l^((n&7)<<3)]
  const int tid = threadIdx.x, b = blockIdx.y, blk = blockIdx.x;
  const int ln = tid & 63, w = tid >> 6, g = ln >> 4;
  const int nq4 = (tid & 15) * 4, lq4 = (tid >> 4) * 4;  // stage: 4l x 4n
  const int nmu = tid >> 2, qmu = tid & 3;

  f32x4 cacc[4];
  #pragma unroll
  for (int j = 0; j < 4; ++j) cacc[j] = (f32x4){0.f, 0.f, 0.f, 0.f};
  float muacc = 0.f;

  for (int t = 0; t < 8; ++t) {
    const int l0 = (blk * 8 + t) * 64;
    __syncthreads();
    {  // stage: read [l][n] quads, transpose in regs, write [n][l] quads
      f16x4 rd[4];
      #pragma unroll
      for (int i = 0; i < 4; ++i)
        rd[i] = *(const f16x4*)&av_g[((size_t)b * LTOT + l0 + lq4 + i) * 64 + nq4];
      #pragma unroll
      for (int j = 0; j < 4; ++j) {
        const int n = nq4 + j;
        f16x4 wr;
        #pragma unroll
        for (int i = 0; i < 4; ++i) wr[i] = rd[i][j];
        *(f16x4*)&AV[n * 64 + (lq4 ^ ((n & 7) << 3))] = wr;
      }
    }
    __syncthreads();
    {  // mu partial: row sums
      const f16x8 a0 = *(const f16x8*)&AV[nmu * 64 + ((qmu * 16) ^ ((nmu & 7) << 3))];
      const f16x8 a1 = *(const f16x8*)&AV[nmu * 64 + ((qmu * 16 + 8) ^ ((nmu & 7) << 3))];
      #pragma unroll
      for (int j = 0; j < 8; ++j) muacc += (float)a0[j] + (float)a1[j];
    }
    // C MFMA: wave w owns rows n = w*16..+16
    const int nA = w * 16 + (ln & 15);
    f16x8 caf[2];
    #pragma unroll
    for (int ks = 0; ks < 2; ++ks)
      caf[ks] = *(const f16x8*)&AV[nA * 64 + ((ks * 32 + g * 8) ^ ((nA & 7) << 3))];
    #pragma unroll
    for (int nct = 0; nct < 4; ++nct) {
      const int nb = nct * 16 + (ln & 15);
      #pragma unroll
      for (int ks = 0; ks < 2; ++ks) {
        const f16x8 cbf = *(const f16x8*)&AV[nb * 64 + ((ks * 32 + g * 8) ^ ((nb & 7) << 3))];
        cacc[nct] = MFMA16(caf[ks], cbf, cacc[nct]);
      }
    }
  }
  float* cp = cpart + (size_t)(b * 216 + blk) * 4096;
  #pragma unroll
  for (int nct = 0; nct < 4; ++nct)
    #pragma unroll
    for (int r = 0; r < 4; ++r)
      cp[(w * 16 + g * 4 + r) * 64 + nct * 16 + (ln & 15)] = cacc[nct][r];
  muacc += __shfl_xor(muacc, 1);
  muacc += __shfl_xor(muacc, 2);
  if (qmu == 0) mupart[(size_t)(b * 216 + blk) * 64 + nmu] = muacc;
}

// ============ P4a: reduce C partials + mu partials ===========================
__global__ void p4a(const float* __restrict__ cpart, const float* __restrict__ mupart,
                    float* __restrict__ csum, float* __restrict__ musum)
{
  const int b = blockIdx.y, bx = blockIdx.x, tid = threadIdx.x;
  if (bx < 64) {
    const int idx = bx * 64 + (tid >> 2), q = tid & 3;
    float s = 0.f;
    for (int k = q; k < 216; k += 4) s += cpart[(size_t)(b * 216 + k) * 4096 + idx];
    s += __shfl_xor(s, 1);
    s += __shfl_xor(s, 2);
    if (q == 0) csum[(size_t)b * 4096 + idx] = s;
  } else if (tid < 64) {
    float s = 0.f;
    for (int k = 0; k < 216; ++k) s += mupart[(size_t)(b * 216 + k) * 64 + tid];
    musum[b * 64 + tid] = s;
  }
}

// ============ P4b: mean = G@mu/L; E[Z^2] = (G C G^T)_mm / L -> mean,rsig =====
__global__ void p4b(const float* __restrict__ csum, const float* __restrict__ musum,
                    const float* __restrict__ g32, float* __restrict__ mr)
{
  __shared__ __align__(16) float CL[4096];
  __shared__ __align__(16) float GLs[32 * 68];
  __shared__ float MUL[64];
  const int tid = threadIdx.x, b = blockIdx.y, bx = blockIdx.x;
  #pragma unroll
  for (int k = 0; k < 16; ++k) CL[k * 256 + tid] = csum[(size_t)b * 4096 + k * 256 + tid];
  #pragma unroll
  for (int k = 0; k < 8; ++k) {
    const int idx = k * 256 + tid;
    const int m_ = idx >> 6, n_ = idx & 63;
    GLs[m_ * 68 + n_] = g32[(size_t)b * 8192 + (bx * 32 + m_) * 64 + n_];
  }
  if (tid < 64) MUL[tid] = musum[b * 64 + tid];
  __syncthreads();
  const int mrow = (tid >> 3) * 68, oct = tid & 7;
  float q = 0.f;
  #pragma unroll
  for (int q4 = 0; q4 < 2; ++q4) {
    const int npb = oct * 8 + q4 * 4;
    float t0 = 0.f, t1 = 0.f, t2 = 0.f, t3 = 0.f;
    #pragma unroll 8
    for (int n = 0; n < 64; ++n) {
      const float4 cv = *(const float4*)&CL[n * 64 + npb];
      const float gv = GLs[mrow + n];
      t0 += gv * cv.x; t1 += gv * cv.y; t2 += gv * cv.z; t3 += gv * cv.w;
    }
    const float4 gq = *(const float4*)&GLs[mrow + npb];
    q += t0 * gq.x + t1 * gq.y + t2 * gq.z + t3 * gq.w;
  }
  q += __shfl_xor(q, 1); q += __shfl_xor(q, 2); q += __shfl_xor(q, 4);
  if (oct == 0) {
    float meanq = 0.f;
    #pragma unroll 8
    for (int n = 0; n < 64; ++n) meanq += GLs[mrow + n] * MUL[n];
    const int m = bx * 32 + (tid >> 3);
    const float mean = meanq / (float)LTOT;
    const float var = fmaxf(q / (float)LTOT - mean * mean, 0.f);
    mr[(b * 128 + m) * 2] = mean;
    mr[(b * 128 + m) * 2 + 1] = rsqrtf(var + EPSV);
  }
}

// ============ P5: Z = G@av (MFMA), write normalized ==========================
// grid (432, B), 4 tiles each (r7 LDS-staged version — best measured).
__global__ __launch_bounds__(256, 2) void p5_z(
    const f16* __restrict__ av_g, const f16* __restrict__ g16,
    const float* __restrict__ mr, float* __restrict__ out)
{
  __shared__ __align__(16) f16 AVT[64 * 64];  // [l][n^((l&7)<<3)]
  const int tid = threadIdx.x, b = blockIdx.y, blk = blockIdx.x;
  const int ln = tid & 63, w = tid >> 6, g = ln >> 4;
  const int lst = tid & 63, pst = tid >> 6;

  // G fragments: wave w owns m = w*32..+32 (2 mct of 16)
  f16x8 gf[2][2];
  float mean_[2][4], rsig_[2][4];
  #pragma unroll
  for (int mct = 0; mct < 2; ++mct) {
    const int mA = w * 32 + mct * 16 + (ln & 15);
    #pragma unroll
    for (int ks = 0; ks < 2; ++ks)
      gf[mct][ks] = *(const f16x8*)&g16[(size_t)b * 8192 + mA * 64 +
                                        (((ks * 4 + g) * 8) ^ ((mA & 7) << 3))];
    #pragma unroll
    for (int r = 0; r < 4; ++r) {
      const int m = w * 32 + mct * 16 + g * 4 + r;
      mean_[mct][r] = mr[(b * 128 + m) * 2];
      rsig_[mct][r] = mr[(b * 128 + m) * 2 + 1];
    }
  }

  for (int t = 0; t < 4; ++t) {
    const int l0 = (blk * 4 + t) * 64;
    __syncthreads();
    {  // stage av tile: straight vector copy with swizzle
      const f16* gp = av_g + ((size_t)b * LTOT + l0 + lst) * 64 + pst * 16;
      const f16x8 a0 = *(const f16x8*)&gp[0];
      const f16x8 a1 = *(const f16x8*)&gp[8];
      *(f16x8*)&AVT[lst * 64 + ((pst * 16) ^ ((lst & 7) << 3))] = a0;
      *(f16x8*)&AVT[lst * 64 + ((pst * 16 + 8) ^ ((lst & 7) << 3))] = a1;
    }
    __syncthreads();
    #pragma unroll
    for (int lt = 0; lt < 4; ++lt) {
      const int l = lt * 16 + (ln & 15);
      f16x8 avf[2];
      #pragma unroll
      for (int ks = 0; ks < 2; ++ks)
        avf[ks] = *(const f16x8*)&AVT[l * 64 + (((ks * 4 + g) * 8) ^ ((l & 7) << 3))];
      #pragma unroll
      for (int mct = 0; mct < 2; ++mct) {
        f32x4 z = {0.f, 0.f, 0.f, 0.f};
        #pragma unroll
        for (int ks = 0; ks < 2; ++ks) z = MFMA16(gf[mct][ks], avf[ks], z);
        #pragma unroll
        for (int r = 0; r < 4; ++r) {
          const int m = w * 32 + mct * 16 + g * 4 + r;
          out[(size_t)(b * 128 + m) * LTOT + l0 + l] =
              (z[r] - mean_[mct][r]) * rsig_[mct][r];
        }
      }
    }
  }
}

extern "C" void kernel_launch(void* const* d_in, const int* in_sizes, int n_in,
                              void* d_out, int out_size, void* d_ws, size_t ws_size,
                              hipStream_t stream)
{
  const float* x  = (const float*)d_in[0];
  const float* WA = (const float*)d_in[1];
  const float* bA = (const float*)d_in[2];
  const float* WB = (const float*)d_in[3];
  const float* bB = (const float*)d_in[4];
  const float* WV = (const float*)d_in[5];
  const float* bV = (const float*)d_in[6];
  float* out = (float*)d_out;

  float* w = (float*)d_ws;
  float* mpart  = w;                        // 2*432*8192 = 7,077,888 f
  float* mpart2 = mpart + 7077888;          // 2*8*8192
  float* separt = mpart2 + 131072;          // 2*432*64
  float* msum   = separt + 55296;           // 2*8192
  float* sesum  = msum + 16384;             // 128
  float* g32    = sesum + 128;              // 2*8192
  f16*   g16f   = (f16*)(g32 + 16384);      // 16,384 f16
  f16*   av_g   = g16f + 16384;             // 2*L*64 f16 = 14,155,776
  float* cpart  = (float*)(av_g + 14155776);// 2*216*4096 = 1,769,472 f
  float* mupart = cpart + 1769472;          // 2*216*64
  float* csum   = mupart + 27648;           // 2*4096
  float* musum  = csum + 8192;              // 128
  float* mr     = musum + 128;              // 512

  p1_proj_m<<<dim3(432, 2), 256, 0, stream>>>(x, WB, bB, WV, bV, av_g, mpart, separt);
  p2a<<<dim3(257, 2), 256, 0, stream>>>(mpart, separt, mpart2, sesum);
  p2a2<<<dim3(32, 2), 256, 0, stream>>>(mpart2, msum);
  p2b<<<dim3(32, 2), 256, 0, stream>>>(WA, bA, msum, sesum, g32, g16f);
  p3_cov<<<dim3(216, 2), 256, 0, stream>>>(av_g, cpart, mupart);
  p4a<<<dim3(65, 2), 256, 0, stream>>>(cpart, mupart, csum, musum);
  p4b<<<dim3(4, 2), 256, 0, stream>>>(csum, musum, g32, mr);
  p5_z<<<dim3(432, 2), 256, 0, stream>>>(av_g, g16f, mr, out);
}

// Round 15
// 113.095 us; speedup vs baseline: 1.5169x; 1.0941x over previous
//
#include <hip/hip_runtime.h>

#define LTOT 110592   // 48*48*48
#define EPSV 1e-5f

typedef _Float16 f16;
typedef __attribute__((ext_vector_type(4))) _Float16 f16x4;
typedef __attribute__((ext_vector_type(8))) _Float16 f16x8;
typedef __attribute__((ext_vector_type(4))) float f32x4;

#define MFMA16(a, b, c) __builtin_amdgcn_mfma_f32_16x16x32_f16(a, b, c, 0, 0, 0)
#define SWC(c) ((((c) ^ ((c) >> 3)) & 7) << 3)

__device__ __forceinline__ f16x8 ld_w8(const float* p) {
  const float4 a = *(const float4*)p;
  const float4 b = *(const float4*)(p + 4);
  f16x8 f;
  f[0] = (f16)a.x; f[1] = (f16)a.y; f[2] = (f16)a.z; f[3] = (f16)a.w;
  f[4] = (f16)b.x; f[5] = (f16)b.y; f[6] = (f16)b.z; f[7] = (f16)b.w;
  return f;
}

// ============ P1: BmT,V proj (MFMA); e->EL; av-softmax->av_g; Mt += EL@XC ====
// (r14 measured-best config; frozen)
__global__ __launch_bounds__(256, 2) void p1_proj_m(
    const float* __restrict__ x,
    const float* __restrict__ WB_, const float* __restrict__ bB_,
    const float* __restrict__ WV_, const float* __restrict__ bV_,
    f16* __restrict__ av_g, float* __restrict__ mpart, float* __restrict__ separt)
{
  __shared__ __align__(16) f16 XT[64 * 128 + 2240];  // [l][c^((l&7)<<3)] (+pad)
  __shared__ __align__(16) f16 XC[128 * 64];  // [c][l^SWC(c)]
  __shared__ __align__(16) f16 EL[64 * 64];   // [n][l^((n&7)<<3)]
  __shared__ __align__(16) f16 AVT[64 * 64];  // [l][n^((l&7)<<3)] (unscaled exp)
  __shared__ float colp[4][64];
  const int tid = threadIdx.x, b = blockIdx.y, blk = blockIdx.x;
  const int ln = tid & 63, w = tid >> 6, g = ln >> 4;

  const int nB = w * 16 + (ln & 15);
  f16x8 wbf[4], wvf[4];
  #pragma unroll
  for (int ks = 0; ks < 4; ++ks) {
    wbf[ks] = ld_w8(&WB_[nB * 128 + ks * 32 + g * 8]);
    wvf[ks] = ld_w8(&WV_[nB * 128 + ks * 32 + g * 8]);
  }
  const float sB = bB_[nB];
  float biasV[4];
  #pragma unroll
  for (int r = 0; r < 4; ++r) biasV[r] = bV_[w * 16 + g * 4 + r];

  f32x4 macc[8];
  #pragma unroll
  for (int i = 0; i < 8; ++i) macc[i] = (f32x4){0.f, 0.f, 0.f, 0.f};
  float se = 0.f;

  // staging thread map: c = co*8+j (j=0..7), l = LQ*4+i (i=0..3)
  const int co = tid >> 4, LQ = tid & 15;
  const size_t xb = (size_t)b * 128 * LTOT;

  float4 xr[8];
  {  // prologue: load tile 0
    const int l0 = blk * 256;
    #pragma unroll
    for (int j = 0; j < 8; ++j)
      xr[j] = *(const float4*)&x[xb + (size_t)(co * 8 + j) * LTOT + l0 + LQ * 4];
  }

  for (int t = 0; t < 4; ++t) {
    const int l0 = (blk * 4 + t) * 64;
    __syncthreads();
    // ---- stage from regs: XT [l][c] (4x f16x8) ----
    #pragma unroll
    for (int i = 0; i < 4; ++i) {
      const int l = LQ * 4 + i;
      f16x8 v;
      #pragma unroll
      for (int j = 0; j < 8; ++j) v[j] = (f16)(((const float*)&xr[j])[i]);
      *(f16x8*)&XT[l * 128 + ((co * 8) ^ ((l & 7) << 3))] = v;
    }
    // ---- stage from regs: XC [c][l] (8x f16x4, SWC swizzle) ----
    #pragma unroll
    for (int j = 0; j < 8; ++j) {
      const int c = co * 8 + j;
      f16x4 q;
      q[0] = (f16)xr[j].x; q[1] = (f16)xr[j].y;
      q[2] = (f16)xr[j].z; q[3] = (f16)xr[j].w;
      *(f16x4*)&XC[c * 64 + ((LQ * 4) ^ SWC(c))] = q;
    }
    __syncthreads();
    // ---- prefetch tile t+1 into regs ----
    if (t < 3) {
      const int l0n = l0 + 64;
      #pragma unroll
      for (int j = 0; j < 8; ++j)
        xr[j] = *(const float4*)&x[xb + (size_t)(co * 8 + j) * LTOT + l0n + LQ * 4];
    }
    // ---- proj: BmT (A=XT,B=WB) and V (A=WV,B=XT) share XT frags ----
    f32x4 aB[4], aV[4];
    #pragma unroll
    for (int lt = 0; lt < 4; ++lt) {
      aB[lt] = (f32x4){0.f, 0.f, 0.f, 0.f};
      aV[lt] = (f32x4){0.f, 0.f, 0.f, 0.f};
      const int l = lt * 16 + (ln & 15);
      #pragma unroll
      for (int ks = 0; ks < 4; ++ks) {
        const f16x8 xf = *(const f16x8*)&XT[l * 128 + (((ks * 4 + g) * 8) ^ ((l & 7) << 3))];
        aB[lt] = MFMA16(xf, wbf[ks], aB[lt]);
        aV[lt] = MFMA16(wvf[ks], xf, aV[lt]);
      }
    }
    // ---- e = exp(BmT + bias) -> EL (f16x4), sumexp ----
    #pragma unroll
    for (int lt = 0; lt < 4; ++lt) {
      f16x4 ev4;
      #pragma unroll
      for (int r = 0; r < 4; ++r) {
        const float e = __expf(aB[lt][r] + sB);
        se += e;
        ev4[r] = (f16)e;
      }
      const int lq = lt * 16 + g * 4;
      *(f16x4*)&EL[nB * 64 + (lq ^ ((nB & 7) << 3))] = ev4;
    }
    // ---- ev = exp(V + bias) -> AVT (unscaled), column-sum partials ----
    float cs[4];
    #pragma unroll
    for (int ct = 0; ct < 4; ++ct) {
      f16x4 av4;
      float s = 0.f;
      #pragma unroll
      for (int r = 0; r < 4; ++r) {
        const float e = __expf(aV[ct][r] + biasV[r]);
        s += e;
        av4[r] = (f16)e;
      }
      cs[ct] = s;
      const int l = ct * 16 + (ln & 15);
      *(f16x4*)&AVT[l * 64 + ((w * 16 + g * 4) ^ ((l & 7) << 3))] = av4;
    }
    #pragma unroll
    for (int ct = 0; ct < 4; ++ct) {
      cs[ct] += __shfl_xor(cs[ct], 16);
      cs[ct] += __shfl_xor(cs[ct], 32);
    }
    {
      const float v = (g == 0) ? cs[0] : (g == 1) ? cs[1] : (g == 2) ? cs[2] : cs[3];
      colp[w][g * 16 + (ln & 15)] = v;
    }
    __syncthreads();
    // ---- scale + store av tile to global [l][n] ----
    {
      const int l = tid >> 2, q = tid & 3;
      const float rs = 1.f / (colp[0][l] + colp[1][l] + colp[2][l] + colp[3][l]);
      f16x8 a0 = *(const f16x8*)&AVT[l * 64 + ((q * 16) ^ ((l & 7) << 3))];
      f16x8 a1 = *(const f16x8*)&AVT[l * 64 + ((q * 16 + 8) ^ ((l & 7) << 3))];
      #pragma unroll
      for (int j = 0; j < 8; ++j) {
        a0[j] = (f16)((float)a0[j] * rs);
        a1[j] = (f16)((float)a1[j] * rs);
      }
      f16* gp = av_g + ((size_t)b * LTOT + l0 + l) * 64 + q * 16;
      *(f16x8*)&gp[0] = a0;
      *(f16x8*)&gp[8] = a1;
    }
    // ---- Mt[n][c] += EL(A) @ XC(B), K=64 ----
    {
      f16x8 el[2];
      #pragma unroll
      for (int ks = 0; ks < 2; ++ks)
        el[ks] = *(const f16x8*)&EL[nB * 64 + ((ks * 32 + g * 8) ^ ((nB & 7) << 3))];
      #pragma unroll
      for (int cblk = 0; cblk < 8; ++cblk) {
        const int c = cblk * 16 + (ln & 15);
        #pragma unroll
        for (int ks = 0; ks < 2; ++ks) {
          const f16x8 xcf = *(const f16x8*)&XC[c * 64 + ((ks * 32 + g * 8) ^ SWC(c))];
          macc[cblk] = MFMA16(el[ks], xcf, macc[cblk]);
        }
      }
    }
  }
  // ---- write Mt partial [n][c] + sumexp partial ----
  float* mp = mpart + (size_t)(b * 432 + blk) * 8192;
  #pragma unroll
  for (int cblk = 0; cblk < 8; ++cblk)
    #pragma unroll
    for (int r = 0; r < 4; ++r)
      mp[(w * 16 + g * 4 + r) * 128 + cblk * 16 + (ln & 15)] = macc[cblk][r];
  se += __shfl_xor(se, 16);
  se += __shfl_xor(se, 32);
  if (ln < 16) separt[(size_t)(b * 432 + blk) * 64 + w * 16 + ln] = se;
}

// ============ KA: p2a (bx<257) ∪ p3 (bx>=257) — both depend only on p1 =======
// p2a: Mt partials 432->8 segs + sumexp 432->1.  p3: C = av@av^T, mu partials.
__global__ __launch_bounds__(256, 2) void ka_red_cov(
    const float* __restrict__ mpart, const float* __restrict__ separt,
    float* __restrict__ mpart2, float* __restrict__ sesum,
    const f16* __restrict__ av_g, float* __restrict__ cpart,
    float* __restrict__ mupart)
{
  __shared__ __align__(16) f16 AV[64 * 64];  // used by p3 branch only
  const int bxa = blockIdx.x, b = blockIdx.y, tid = threadIdx.x;
  if (bxa < 257) {
    // ---------------- p2a body (bx = bxa) ----------------
    const int bx = bxa;
    if (bx < 256) {
      const int seg = bx >> 5, chunk = bx & 31;
      const int idx = chunk * 256 + tid;
      float s = 0.f;
      for (int j = 0; j < 54; ++j)
        s += mpart[(size_t)(b * 432 + seg * 54 + j) * 8192 + idx];
      mpart2[(size_t)(b * 8 + seg) * 8192 + idx] = s;
    } else if (tid < 64) {
      float s = 0.f;
      for (int k = 0; k < 432; ++k) s += separt[(size_t)(b * 432 + k) * 64 + tid];
      sesum[b * 64 + tid] = s;
    }
    return;
  }
  // ---------------- p3 body (blk = bxa - 257) ----------------
  const int blk = bxa - 257;
  const int ln = tid & 63, w = tid >> 6, g = ln >> 4;
  const int nq4 = (tid & 15) * 4, lq4 = (tid >> 4) * 4;  // stage: 4l x 4n
  const int nmu = tid >> 2, qmu = tid & 3;

  f32x4 cacc[4];
  #pragma unroll
  for (int j = 0; j < 4; ++j) cacc[j] = (f32x4){0.f, 0.f, 0.f, 0.f};
  float muacc = 0.f;

  for (int t = 0; t < 8; ++t) {
    const int l0 = (blk * 8 + t) * 64;
    __syncthreads();
    {  // stage: read [l][n] quads, transpose in regs, write [n][l] quads
      f16x4 rd[4];
      #pragma unroll
      for (int i = 0; i < 4; ++i)
        rd[i] = *(const f16x4*)&av_g[((size_t)b * LTOT + l0 + lq4 + i) * 64 + nq4];
      #pragma unroll
      for (int j = 0; j < 4; ++j) {
        const int n = nq4 + j;
        f16x4 wr;
        #pragma unroll
        for (int i = 0; i < 4; ++i) wr[i] = rd[i][j];
        *(f16x4*)&AV[n * 64 + (lq4 ^ ((n & 7) << 3))] = wr;
      }
    }
    __syncthreads();
    {  // mu partial: row sums
      const f16x8 a0 = *(const f16x8*)&AV[nmu * 64 + ((qmu * 16) ^ ((nmu & 7) << 3))];
      const f16x8 a1 = *(const f16x8*)&AV[nmu * 64 + ((qmu * 16 + 8) ^ ((nmu & 7) << 3))];
      #pragma unroll
      for (int j = 0; j < 8; ++j) muacc += (float)a0[j] + (float)a1[j];
    }
    // C MFMA: wave w owns rows n = w*16..+16
    const int nA = w * 16 + (ln & 15);
    f16x8 caf[2];
    #pragma unroll
    for (int ks = 0; ks < 2; ++ks)
      caf[ks] = *(const f16x8*)&AV[nA * 64 + ((ks * 32 + g * 8) ^ ((nA & 7) << 3))];
    #pragma unroll
    for (int nct = 0; nct < 4; ++nct) {
      const int nb = nct * 16 + (ln & 15);
      #pragma unroll
      for (int ks = 0; ks < 2; ++ks) {
        const f16x8 cbf = *(const f16x8*)&AV[nb * 64 + ((ks * 32 + g * 8) ^ ((nb & 7) << 3))];
        cacc[nct] = MFMA16(caf[ks], cbf, cacc[nct]);
      }
    }
  }
  float* cp = cpart + (size_t)(b * 216 + blk) * 4096;
  #pragma unroll
  for (int nct = 0; nct < 4; ++nct)
    #pragma unroll
    for (int r = 0; r < 4; ++r)
      cp[(w * 16 + g * 4 + r) * 64 + nct * 16 + (ln & 15)] = cacc[nct][r];
  muacc += __shfl_xor(muacc, 1);
  muacc += __shfl_xor(muacc, 2);
  if (qmu == 0) mupart[(size_t)(b * 216 + blk) * 64 + nmu] = muacc;
}

// ============ KB: p2a2 (bx<32) ∪ p4a (bx>=32) — both depend only on KA =======
__global__ void kb_red(const float* __restrict__ mpart2, float* __restrict__ msum,
                       const float* __restrict__ cpart, const float* __restrict__ mupart,
                       float* __restrict__ csum, float* __restrict__ musum)
{
  const int bxa = blockIdx.x, b = blockIdx.y, tid = threadIdx.x;
  if (bxa < 32) {
    // ---------------- p2a2 body ----------------
    const int idx = bxa * 256 + tid;
    float s = 0.f;
    #pragma unroll
    for (int k = 0; k < 8; ++k) s += mpart2[(size_t)(b * 8 + k) * 8192 + idx];
    msum[(size_t)b * 8192 + idx] = s;
    return;
  }
  // ---------------- p4a body (bx = bxa - 32) ----------------
  const int bx = bxa - 32;
  if (bx < 64) {
    const int idx = bx * 64 + (tid >> 2), q = tid & 3;
    float s = 0.f;
    for (int k = q; k < 216; k += 4) s += cpart[(size_t)(b * 216 + k) * 4096 + idx];
    s += __shfl_xor(s, 1);
    s += __shfl_xor(s, 2);
    if (q == 0) csum[(size_t)b * 4096 + idx] = s;
  } else if (tid < 64) {
    float s = 0.f;
    for (int k = 0; k < 216; ++k) s += mupart[(size_t)(b * 216 + k) * 64 + tid];
    musum[b * 64 + tid] = s;
  }
}

// ============ P2b: G[m,n] = (WA@M)/sesum + bA; f32 [m][n] + swizzled f16 =====
__global__ void p2b(const float* __restrict__ WA_, const float* __restrict__ bA_,
                    const float* __restrict__ msum, const float* __restrict__ sesum,
                    float* __restrict__ g32, f16* __restrict__ g16)
{
  const int b = blockIdx.y;
  const int idx = blockIdx.x * 256 + threadIdx.x;
  const int m = idx >> 6, n = idx & 63;
  float s = 0.f;
  #pragma unroll 4
  for (int c = 0; c < 128; ++c) s += WA_[m * 128 + c] * msum[(size_t)b * 8192 + n * 128 + c];
  const float gv = s / sesum[b * 64 + n] + bA_[m];
  g32[(size_t)b * 8192 + m * 64 + n] = gv;
  g16[(size_t)b * 8192 + m * 64 + (n ^ ((m & 7) << 3))] = (f16)gv;
}

// ============ P4b: mean = G@mu/L; E[Z^2] = (G C G^T)_mm / L -> mean,rsig =====
__global__ void p4b(const float* __restrict__ csum, const float* __restrict__ musum,
                    const float* __restrict__ g32, float* __restrict__ mr)
{
  __shared__ __align__(16) float CL[4096];
  __shared__ __align__(16) float GLs[32 * 68];
  __shared__ float MUL[64];
  const int tid = threadIdx.x, b = blockIdx.y, bx = blockIdx.x;
  #pragma unroll
  for (int k = 0; k < 16; ++k) CL[k * 256 + tid] = csum[(size_t)b * 4096 + k * 256 + tid];
  #pragma unroll
  for (int k = 0; k < 8; ++k) {
    const int idx = k * 256 + tid;
    const int m_ = idx >> 6, n_ = idx & 63;
    GLs[m_ * 68 + n_] = g32[(size_t)b * 8192 + (bx * 32 + m_) * 64 + n_];
  }
  if (tid < 64) MUL[tid] = musum[b * 64 + tid];
  __syncthreads();
  const int mrow = (tid >> 3) * 68, oct = tid & 7;
  float q = 0.f;
  #pragma unroll
  for (int q4 = 0; q4 < 2; ++q4) {
    const int npb = oct * 8 + q4 * 4;
    float t0 = 0.f, t1 = 0.f, t2 = 0.f, t3 = 0.f;
    #pragma unroll 8
    for (int n = 0; n < 64; ++n) {
      const float4 cv = *(const float4*)&CL[n * 64 + npb];
      const float gv = GLs[mrow + n];
      t0 += gv * cv.x; t1 += gv * cv.y; t2 += gv * cv.z; t3 += gv * cv.w;
    }
    const float4 gq = *(const float4*)&GLs[mrow + npb];
    q += t0 * gq.x + t1 * gq.y + t2 * gq.z + t3 * gq.w;
  }
  q += __shfl_xor(q, 1); q += __shfl_xor(q, 2); q += __shfl_xor(q, 4);
  if (oct == 0) {
    float meanq = 0.f;
    #pragma unroll 8
    for (int n = 0; n < 64; ++n) meanq += GLs[mrow + n] * MUL[n];
    const int m = bx * 32 + (tid >> 3);
    const float mean = meanq / (float)LTOT;
    const float var = fmaxf(q / (float)LTOT - mean * mean, 0.f);
    mr[(b * 128 + m) * 2] = mean;
    mr[(b * 128 + m) * 2 + 1] = rsqrtf(var + EPSV);
  }
}

// ============ P5: Z = G@av (MFMA), write normalized ==========================
// grid (432, B), 4 tiles each (r7 LDS-staged version — best measured).
__global__ __launch_bounds__(256, 2) void p5_z(
    const f16* __restrict__ av_g, const f16* __restrict__ g16,
    const float* __restrict__ mr, float* __restrict__ out)
{
  __shared__ __align__(16) f16 AVT[64 * 64];  // [l][n^((l&7)<<3)]
  const int tid = threadIdx.x, b = blockIdx.y, blk = blockIdx.x;
  const int ln = tid & 63, w = tid >> 6, g = ln >> 4;
  const int lst = tid & 63, pst = tid >> 6;

  // G fragments: wave w owns m = w*32..+32 (2 mct of 16)
  f16x8 gf[2][2];
  float mean_[2][4], rsig_[2][4];
  #pragma unroll
  for (int mct = 0; mct < 2; ++mct) {
    const int mA = w * 32 + mct * 16 + (ln & 15);
    #pragma unroll
    for (int ks = 0; ks < 2; ++ks)
      gf[mct][ks] = *(const f16x8*)&g16[(size_t)b * 8192 + mA * 64 +
                                        (((ks * 4 + g) * 8) ^ ((mA & 7) << 3))];
    #pragma unroll
    for (int r = 0; r < 4; ++r) {
      const int m = w * 32 + mct * 16 + g * 4 + r;
      mean_[mct][r] = mr[(b * 128 + m) * 2];
      rsig_[mct][r] = mr[(b * 128 + m) * 2 + 1];
    }
  }

  for (int t = 0; t < 4; ++t) {
    const int l0 = (blk * 4 + t) * 64;
    __syncthreads();
    {  // stage av tile: straight vector copy with swizzle
      const f16* gp = av_g + ((size_t)b * LTOT + l0 + lst) * 64 + pst * 16;
      const f16x8 a0 = *(const f16x8*)&gp[0];
      const f16x8 a1 = *(const f16x8*)&gp[8];
      *(f16x8*)&AVT[lst * 64 + ((pst * 16) ^ ((lst & 7) << 3))] = a0;
      *(f16x8*)&AVT[lst * 64 + ((pst * 16 + 8) ^ ((lst & 7) << 3))] = a1;
    }
    __syncthreads();
    #pragma unroll
    for (int lt = 0; lt < 4; ++lt) {
      const int l = lt * 16 + (ln & 15);
      f16x8 avf[2];
      #pragma unroll
      for (int ks = 0; ks < 2; ++ks)
        avf[ks] = *(const f16x8*)&AVT[l * 64 + (((ks * 4 + g) * 8) ^ ((l & 7) << 3))];
      #pragma unroll
      for (int mct = 0; mct < 2; ++mct) {
        f32x4 z = {0.f, 0.f, 0.f, 0.f};
        #pragma unroll
        for (int ks = 0; ks < 2; ++ks) z = MFMA16(gf[mct][ks], avf[ks], z);
        #pragma unroll
        for (int r = 0; r < 4; ++r) {
          const int m = w * 32 + mct * 16 + g * 4 + r;
          out[(size_t)(b * 128 + m) * LTOT + l0 + l] =
              (z[r] - mean_[mct][r]) * rsig_[mct][r];
        }
      }
    }
  }
}

extern "C" void kernel_launch(void* const* d_in, const int* in_sizes, int n_in,
                              void* d_out, int out_size, void* d_ws, size_t ws_size,
                              hipStream_t stream)
{
  const float* x  = (const float*)d_in[0];
  const float* WA = (const float*)d_in[1];
  const float* bA = (const float*)d_in[2];
  const float* WB = (const float*)d_in[3];
  const float* bB = (const float*)d_in[4];
  const float* WV = (const float*)d_in[5];
  const float* bV = (const float*)d_in[6];
  float* out = (float*)d_out;

  float* w = (float*)d_ws;
  float* mpart  = w;                        // 2*432*8192 = 7,077,888 f
  float* mpart2 = mpart + 7077888;          // 2*8*8192
  float* separt = mpart2 + 131072;          // 2*432*64
  float* msum   = separt + 55296;           // 2*8192
  float* sesum  = msum + 16384;             // 128
  float* g32    = sesum + 128;              // 2*8192
  f16*   g16f   = (f16*)(g32 + 16384);      // 16,384 f16
  f16*   av_g   = g16f + 16384;             // 2*L*64 f16 = 14,155,776
  float* cpart  = (float*)(av_g + 14155776);// 2*216*4096 = 1,769,472 f
  float* mupart = cpart + 1769472;          // 2*216*64
  float* csum   = mupart + 27648;           // 2*4096
  float* musum  = csum + 8192;              // 128
  float* mr     = musum + 128;              // 512

  p1_proj_m<<<dim3(432, 2), 256, 0, stream>>>(x, WB, bB, WV, bV, av_g, mpart, separt);
  ka_red_cov<<<dim3(473, 2), 256, 0, stream>>>(mpart, separt, mpart2, sesum,
                                               av_g, cpart, mupart);
  kb_red<<<dim3(97, 2), 256, 0, stream>>>(mpart2, msum, cpart, mupart, csum, musum);
  p2b<<<dim3(32, 2), 256, 0, stream>>>(WA, bA, msum, sesum, g32, g16f);
  p4b<<<dim3(4, 2), 256, 0, stream>>>(csum, musum, g32, mr);
  p5_z<<<dim3(432, 2), 256, 0, stream>>>(av_g, g16f, mr, out);
}

// Round 16
// 110.017 us; speedup vs baseline: 1.5594x; 1.0280x over previous
//
#include <hip/hip_runtime.h>

#define LTOT 110592   // 48*48*48
#define EPSV 1e-5f

typedef _Float16 f16;
typedef __attribute__((ext_vector_type(4))) _Float16 f16x4;
typedef __attribute__((ext_vector_type(8))) _Float16 f16x8;
typedef __attribute__((ext_vector_type(4))) float f32x4;

#define MFMA16(a, b, c) __builtin_amdgcn_mfma_f32_16x16x32_f16(a, b, c, 0, 0, 0)
#define SWC(c) ((((c) ^ ((c) >> 3)) & 7) << 3)

__device__ __forceinline__ f16x8 ld_w8(const float* p) {
  const float4 a = *(const float4*)p;
  const float4 b = *(const float4*)(p + 4);
  f16x8 f;
  f[0] = (f16)a.x; f[1] = (f16)a.y; f[2] = (f16)a.z; f[3] = (f16)a.w;
  f[4] = (f16)b.x; f[5] = (f16)b.y; f[6] = (f16)b.z; f[7] = (f16)b.w;
  return f;
}

// ============ P1: BmT,V proj (MFMA); e->EL; av-softmax->av_g; Mt += EL@XC ====
// (r14 measured-best config; r16: mpart stored as f16)
__global__ __launch_bounds__(256, 2) void p1_proj_m(
    const float* __restrict__ x,
    const float* __restrict__ WB_, const float* __restrict__ bB_,
    const float* __restrict__ WV_, const float* __restrict__ bV_,
    f16* __restrict__ av_g, f16* __restrict__ mpart, float* __restrict__ separt)
{
  __shared__ __align__(16) f16 XT[64 * 128 + 2240];  // [l][c^((l&7)<<3)] (+pad)
  __shared__ __align__(16) f16 XC[128 * 64];  // [c][l^SWC(c)]
  __shared__ __align__(16) f16 EL[64 * 64];   // [n][l^((n&7)<<3)]
  __shared__ __align__(16) f16 AVT[64 * 64];  // [l][n^((l&7)<<3)] (unscaled exp)
  __shared__ float colp[4][64];
  const int tid = threadIdx.x, b = blockIdx.y, blk = blockIdx.x;
  const int ln = tid & 63, w = tid >> 6, g = ln >> 4;

  const int nB = w * 16 + (ln & 15);
  f16x8 wbf[4], wvf[4];
  #pragma unroll
  for (int ks = 0; ks < 4; ++ks) {
    wbf[ks] = ld_w8(&WB_[nB * 128 + ks * 32 + g * 8]);
    wvf[ks] = ld_w8(&WV_[nB * 128 + ks * 32 + g * 8]);
  }
  const float sB = bB_[nB];
  float biasV[4];
  #pragma unroll
  for (int r = 0; r < 4; ++r) biasV[r] = bV_[w * 16 + g * 4 + r];

  f32x4 macc[8];
  #pragma unroll
  for (int i = 0; i < 8; ++i) macc[i] = (f32x4){0.f, 0.f, 0.f, 0.f};
  float se = 0.f;

  // staging thread map: c = co*8+j (j=0..7), l = LQ*4+i (i=0..3)
  const int co = tid >> 4, LQ = tid & 15;
  const size_t xb = (size_t)b * 128 * LTOT;

  float4 xr[8];
  {  // prologue: load tile 0
    const int l0 = blk * 256;
    #pragma unroll
    for (int j = 0; j < 8; ++j)
      xr[j] = *(const float4*)&x[xb + (size_t)(co * 8 + j) * LTOT + l0 + LQ * 4];
  }

  for (int t = 0; t < 4; ++t) {
    const int l0 = (blk * 4 + t) * 64;
    __syncthreads();
    // ---- stage from regs: XT [l][c] (4x f16x8) ----
    #pragma unroll
    for (int i = 0; i < 4; ++i) {
      const int l = LQ * 4 + i;
      f16x8 v;
      #pragma unroll
      for (int j = 0; j < 8; ++j) v[j] = (f16)(((const float*)&xr[j])[i]);
      *(f16x8*)&XT[l * 128 + ((co * 8) ^ ((l & 7) << 3))] = v;
    }
    // ---- stage from regs: XC [c][l] (8x f16x4, SWC swizzle) ----
    #pragma unroll
    for (int j = 0; j < 8; ++j) {
      const int c = co * 8 + j;
      f16x4 q;
      q[0] = (f16)xr[j].x; q[1] = (f16)xr[j].y;
      q[2] = (f16)xr[j].z; q[3] = (f16)xr[j].w;
      *(f16x4*)&XC[c * 64 + ((LQ * 4) ^ SWC(c))] = q;
    }
    __syncthreads();
    // ---- prefetch tile t+1 into regs ----
    if (t < 3) {
      const int l0n = l0 + 64;
      #pragma unroll
      for (int j = 0; j < 8; ++j)
        xr[j] = *(const float4*)&x[xb + (size_t)(co * 8 + j) * LTOT + l0n + LQ * 4];
    }
    // ---- proj: BmT (A=XT,B=WB) and V (A=WV,B=XT) share XT frags ----
    f32x4 aB[4], aV[4];
    #pragma unroll
    for (int lt = 0; lt < 4; ++lt) {
      aB[lt] = (f32x4){0.f, 0.f, 0.f, 0.f};
      aV[lt] = (f32x4){0.f, 0.f, 0.f, 0.f};
      const int l = lt * 16 + (ln & 15);
      #pragma unroll
      for (int ks = 0; ks < 4; ++ks) {
        const f16x8 xf = *(const f16x8*)&XT[l * 128 + (((ks * 4 + g) * 8) ^ ((l & 7) << 3))];
        aB[lt] = MFMA16(xf, wbf[ks], aB[lt]);
        aV[lt] = MFMA16(wvf[ks], xf, aV[lt]);
      }
    }
    // ---- e = exp(BmT + bias) -> EL (f16x4), sumexp ----
    #pragma unroll
    for (int lt = 0; lt < 4; ++lt) {
      f16x4 ev4;
      #pragma unroll
      for (int r = 0; r < 4; ++r) {
        const float e = __expf(aB[lt][r] + sB);
        se += e;
        ev4[r] = (f16)e;
      }
      const int lq = lt * 16 + g * 4;
      *(f16x4*)&EL[nB * 64 + (lq ^ ((nB & 7) << 3))] = ev4;
    }
    // ---- ev = exp(V + bias) -> AVT (unscaled), column-sum partials ----
    float cs[4];
    #pragma unroll
    for (int ct = 0; ct < 4; ++ct) {
      f16x4 av4;
      float s = 0.f;
      #pragma unroll
      for (int r = 0; r < 4; ++r) {
        const float e = __expf(aV[ct][r] + biasV[r]);
        s += e;
        av4[r] = (f16)e;
      }
      cs[ct] = s;
      const int l = ct * 16 + (ln & 15);
      *(f16x4*)&AVT[l * 64 + ((w * 16 + g * 4) ^ ((l & 7) << 3))] = av4;
    }
    #pragma unroll
    for (int ct = 0; ct < 4; ++ct) {
      cs[ct] += __shfl_xor(cs[ct], 16);
      cs[ct] += __shfl_xor(cs[ct], 32);
    }
    {
      const float v = (g == 0) ? cs[0] : (g == 1) ? cs[1] : (g == 2) ? cs[2] : cs[3];
      colp[w][g * 16 + (ln & 15)] = v;
    }
    __syncthreads();
    // ---- scale + store av tile to global [l][n] ----
    {
      const int l = tid >> 2, q = tid & 3;
      const float rs = 1.f / (colp[0][l] + colp[1][l] + colp[2][l] + colp[3][l]);
      f16x8 a0 = *(const f16x8*)&AVT[l * 64 + ((q * 16) ^ ((l & 7) << 3))];
      f16x8 a1 = *(const f16x8*)&AVT[l * 64 + ((q * 16 + 8) ^ ((l & 7) << 3))];
      #pragma unroll
      for (int j = 0; j < 8; ++j) {
        a0[j] = (f16)((float)a0[j] * rs);
        a1[j] = (f16)((float)a1[j] * rs);
      }
      f16* gp = av_g + ((size_t)b * LTOT + l0 + l) * 64 + q * 16;
      *(f16x8*)&gp[0] = a0;
      *(f16x8*)&gp[8] = a1;
    }
    // ---- Mt[n][c] += EL(A) @ XC(B), K=64 ----
    {
      f16x8 el[2];
      #pragma unroll
      for (int ks = 0; ks < 2; ++ks)
        el[ks] = *(const f16x8*)&EL[nB * 64 + ((ks * 32 + g * 8) ^ ((nB & 7) << 3))];
      #pragma unroll
      for (int cblk = 0; cblk < 8; ++cblk) {
        const int c = cblk * 16 + (ln & 15);
        #pragma unroll
        for (int ks = 0; ks < 2; ++ks) {
          const f16x8 xcf = *(const f16x8*)&XC[c * 64 + ((ks * 32 + g * 8) ^ SWC(c))];
          macc[cblk] = MFMA16(el[ks], xcf, macc[cblk]);
        }
      }
    }
  }
  // ---- write Mt partial [n][c] (f16) + sumexp partial ----
  f16* mp = mpart + (size_t)(b * 432 + blk) * 8192;
  #pragma unroll
  for (int cblk = 0; cblk < 8; ++cblk)
    #pragma unroll
    for (int r = 0; r < 4; ++r)
      mp[(w * 16 + g * 4 + r) * 128 + cblk * 16 + (ln & 15)] = (f16)macc[cblk][r];
  se += __shfl_xor(se, 16);
  se += __shfl_xor(se, 32);
  if (ln < 16) separt[(size_t)(b * 432 + blk) * 64 + w * 16 + ln] = se;
}

// ============ KA: p2a (bx<257) ∪ p3 (bx>=257) — both depend only on p1 =======
// p2a: Mt partials (f16) 432->8 segs (f32) + sumexp 432->1.
// p3: C = av@av^T -> cpart (f16), mu partials.
__global__ __launch_bounds__(256, 2) void ka_red_cov(
    const f16* __restrict__ mpart, const float* __restrict__ separt,
    float* __restrict__ mpart2, float* __restrict__ sesum,
    const f16* __restrict__ av_g, f16* __restrict__ cpart,
    float* __restrict__ mupart)
{
  __shared__ __align__(16) f16 AV[64 * 64];  // used by p3 branch only
  const int bxa = blockIdx.x, b = blockIdx.y, tid = threadIdx.x;
  if (bxa < 257) {
    // ---------------- p2a body ----------------
    const int bx = bxa;
    if (bx < 256) {
      const int seg = bx >> 5, chunk = bx & 31;
      const int idx = chunk * 256 + tid;
      float s = 0.f;
      for (int j = 0; j < 54; ++j)
        s += (float)mpart[(size_t)(b * 432 + seg * 54 + j) * 8192 + idx];
      mpart2[(size_t)(b * 8 + seg) * 8192 + idx] = s;
    } else if (tid < 64) {
      float s = 0.f;
      for (int k = 0; k < 432; ++k) s += separt[(size_t)(b * 432 + k) * 64 + tid];
      sesum[b * 64 + tid] = s;
    }
    return;
  }
  // ---------------- p3 body (blk = bxa - 257) ----------------
  const int blk = bxa - 257;
  const int ln = tid & 63, w = tid >> 6, g = ln >> 4;
  const int nq4 = (tid & 15) * 4, lq4 = (tid >> 4) * 4;  // stage: 4l x 4n
  const int nmu = tid >> 2, qmu = tid & 3;

  f32x4 cacc[4];
  #pragma unroll
  for (int j = 0; j < 4; ++j) cacc[j] = (f32x4){0.f, 0.f, 0.f, 0.f};
  float muacc = 0.f;

  for (int t = 0; t < 8; ++t) {
    const int l0 = (blk * 8 + t) * 64;
    __syncthreads();
    {  // stage: read [l][n] quads, transpose in regs, write [n][l] quads
      f16x4 rd[4];
      #pragma unroll
      for (int i = 0; i < 4; ++i)
        rd[i] = *(const f16x4*)&av_g[((size_t)b * LTOT + l0 + lq4 + i) * 64 + nq4];
      #pragma unroll
      for (int j = 0; j < 4; ++j) {
        const int n = nq4 + j;
        f16x4 wr;
        #pragma unroll
        for (int i = 0; i < 4; ++i) wr[i] = rd[i][j];
        *(f16x4*)&AV[n * 64 + (lq4 ^ ((n & 7) << 3))] = wr;
      }
    }
    __syncthreads();
    {  // mu partial: row sums
      const f16x8 a0 = *(const f16x8*)&AV[nmu * 64 + ((qmu * 16) ^ ((nmu & 7) << 3))];
      const f16x8 a1 = *(const f16x8*)&AV[nmu * 64 + ((qmu * 16 + 8) ^ ((nmu & 7) << 3))];
      #pragma unroll
      for (int j = 0; j < 8; ++j) muacc += (float)a0[j] + (float)a1[j];
    }
    // C MFMA: wave w owns rows n = w*16..+16
    const int nA = w * 16 + (ln & 15);
    f16x8 caf[2];
    #pragma unroll
    for (int ks = 0; ks < 2; ++ks)
      caf[ks] = *(const f16x8*)&AV[nA * 64 + ((ks * 32 + g * 8) ^ ((nA & 7) << 3))];
    #pragma unroll
    for (int nct = 0; nct < 4; ++nct) {
      const int nb = nct * 16 + (ln & 15);
      #pragma unroll
      for (int ks = 0; ks < 2; ++ks) {
        const f16x8 cbf = *(const f16x8*)&AV[nb * 64 + ((ks * 32 + g * 8) ^ ((nb & 7) << 3))];
        cacc[nct] = MFMA16(caf[ks], cbf, cacc[nct]);
      }
    }
  }
  f16* cp = cpart + (size_t)(b * 216 + blk) * 4096;
  #pragma unroll
  for (int nct = 0; nct < 4; ++nct)
    #pragma unroll
    for (int r = 0; r < 4; ++r)
      cp[(w * 16 + g * 4 + r) * 64 + nct * 16 + (ln & 15)] = (f16)cacc[nct][r];
  muacc += __shfl_xor(muacc, 1);
  muacc += __shfl_xor(muacc, 2);
  if (qmu == 0) mupart[(size_t)(b * 216 + blk) * 64 + nmu] = muacc;
}

// ============ KB: p2a2 (bx<32) ∪ p4a (bx>=32) — both depend only on KA =======
__global__ void kb_red(const float* __restrict__ mpart2, float* __restrict__ msum,
                       const f16* __restrict__ cpart, const float* __restrict__ mupart,
                       float* __restrict__ csum, float* __restrict__ musum)
{
  const int bxa = blockIdx.x, b = blockIdx.y, tid = threadIdx.x;
  if (bxa < 32) {
    // ---------------- p2a2 body ----------------
    const int idx = bxa * 256 + tid;
    float s = 0.f;
    #pragma unroll
    for (int k = 0; k < 8; ++k) s += mpart2[(size_t)(b * 8 + k) * 8192 + idx];
    msum[(size_t)b * 8192 + idx] = s;
    return;
  }
  // ---------------- p4a body (bx = bxa - 32) ----------------
  const int bx = bxa - 32;
  if (bx < 64) {
    const int idx = bx * 64 + (tid >> 2), q = tid & 3;
    float s = 0.f;
    for (int k = q; k < 216; k += 4) s += (float)cpart[(size_t)(b * 216 + k) * 4096 + idx];
    s += __shfl_xor(s, 1);
    s += __shfl_xor(s, 2);
    if (q == 0) csum[(size_t)b * 4096 + idx] = s;
  } else if (tid < 64) {
    float s = 0.f;
    for (int k = 0; k < 216; ++k) s += mupart[(size_t)(b * 216 + k) * 64 + tid];
    musum[b * 64 + tid] = s;
  }
}

// ============ P2b: G[m,n] = (WA@M)/sesum + bA; f32 [m][n] + swizzled f16 =====
__global__ void p2b(const float* __restrict__ WA_, const float* __restrict__ bA_,
                    const float* __restrict__ msum, const float* __restrict__ sesum,
                    float* __restrict__ g32, f16* __restrict__ g16)
{
  const int b = blockIdx.y;
  const int idx = blockIdx.x * 256 + threadIdx.x;
  const int m = idx >> 6, n = idx & 63;
  float s = 0.f;
  #pragma unroll 4
  for (int c = 0; c < 128; ++c) s += WA_[m * 128 + c] * msum[(size_t)b * 8192 + n * 128 + c];
  const float gv = s / sesum[b * 64 + n] + bA_[m];
  g32[(size_t)b * 8192 + m * 64 + n] = gv;
  g16[(size_t)b * 8192 + m * 64 + (n ^ ((m & 7) << 3))] = (f16)gv;
}

// ============ P4b: mean = G@mu/L; E[Z^2] = (G C G^T)_mm / L -> mean,rsig =====
__global__ void p4b(const float* __restrict__ csum, const float* __restrict__ musum,
                    const float* __restrict__ g32, float* __restrict__ mr)
{
  __shared__ __align__(16) float CL[4096];
  __shared__ __align__(16) float GLs[32 * 68];
  __shared__ float MUL[64];
  const int tid = threadIdx.x, b = blockIdx.y, bx = blockIdx.x;
  #pragma unroll
  for (int k = 0; k < 16; ++k) CL[k * 256 + tid] = csum[(size_t)b * 4096 + k * 256 + tid];
  #pragma unroll
  for (int k = 0; k < 8; ++k) {
    const int idx = k * 256 + tid;
    const int m_ = idx >> 6, n_ = idx & 63;
    GLs[m_ * 68 + n_] = g32[(size_t)b * 8192 + (bx * 32 + m_) * 64 + n_];
  }
  if (tid < 64) MUL[tid] = musum[b * 64 + tid];
  __syncthreads();
  const int mrow = (tid >> 3) * 68, oct = tid & 7;
  float q = 0.f;
  #pragma unroll
  for (int q4 = 0; q4 < 2; ++q4) {
    const int npb = oct * 8 + q4 * 4;
    float t0 = 0.f, t1 = 0.f, t2 = 0.f, t3 = 0.f;
    #pragma unroll 8
    for (int n = 0; n < 64; ++n) {
      const float4 cv = *(const float4*)&CL[n * 64 + npb];
      const float gv = GLs[mrow + n];
      t0 += gv * cv.x; t1 += gv * cv.y; t2 += gv * cv.z; t3 += gv * cv.w;
    }
    const float4 gq = *(const float4*)&GLs[mrow + npb];
    q += t0 * gq.x + t1 * gq.y + t2 * gq.z + t3 * gq.w;
  }
  q += __shfl_xor(q, 1); q += __shfl_xor(q, 2); q += __shfl_xor(q, 4);
  if (oct == 0) {
    float meanq = 0.f;
    #pragma unroll 8
    for (int n = 0; n < 64; ++n) meanq += GLs[mrow + n] * MUL[n];
    const int m = bx * 32 + (tid >> 3);
    const float mean = meanq / (float)LTOT;
    const float var = fmaxf(q / (float)LTOT - mean * mean, 0.f);
    mr[(b * 128 + m) * 2] = mean;
    mr[(b * 128 + m) * 2 + 1] = rsqrtf(var + EPSV);
  }
}

// ============ P5: Z = G@av (MFMA), write normalized ==========================
// grid (432, B), 4 tiles each (r7 LDS-staged version — best measured).
__global__ __launch_bounds__(256, 2) void p5_z(
    const f16* __restrict__ av_g, const f16* __restrict__ g16,
    const float* __restrict__ mr, float* __restrict__ out)
{
  __shared__ __align__(16) f16 AVT[64 * 64];  // [l][n^((l&7)<<3)]
  const int tid = threadIdx.x, b = blockIdx.y, blk = blockIdx.x;
  const int ln = tid & 63, w = tid >> 6, g = ln >> 4;
  const int lst = tid & 63, pst = tid >> 6;

  // G fragments: wave w owns m = w*32..+32 (2 mct of 16)
  f16x8 gf[2][2];
  float mean_[2][4], rsig_[2][4];
  #pragma unroll
  for (int mct = 0; mct < 2; ++mct) {
    const int mA = w * 32 + mct * 16 + (ln & 15);
    #pragma unroll
    for (int ks = 0; ks < 2; ++ks)
      gf[mct][ks] = *(const f16x8*)&g16[(size_t)b * 8192 + mA * 64 +
                                        (((ks * 4 + g) * 8) ^ ((mA & 7) << 3))];
    #pragma unroll
    for (int r = 0; r < 4; ++r) {
      const int m = w * 32 + mct * 16 + g * 4 + r;
      mean_[mct][r] = mr[(b * 128 + m) * 2];
      rsig_[mct][r] = mr[(b * 128 + m) * 2 + 1];
    }
  }

  for (int t = 0; t < 4; ++t) {
    const int l0 = (blk * 4 + t) * 64;
    __syncthreads();
    {  // stage av tile: straight vector copy with swizzle
      const f16* gp = av_g + ((size_t)b * LTOT + l0 + lst) * 64 + pst * 16;
      const f16x8 a0 = *(const f16x8*)&gp[0];
      const f16x8 a1 = *(const f16x8*)&gp[8];
      *(f16x8*)&AVT[lst * 64 + ((pst * 16) ^ ((lst & 7) << 3))] = a0;
      *(f16x8*)&AVT[lst * 64 + ((pst * 16 + 8) ^ ((lst & 7) << 3))] = a1;
    }
    __syncthreads();
    #pragma unroll
    for (int lt = 0; lt < 4; ++lt) {
      const int l = lt * 16 + (ln & 15);
      f16x8 avf[2];
      #pragma unroll
      for (int ks = 0; ks < 2; ++ks)
        avf[ks] = *(const f16x8*)&AVT[l * 64 + (((ks * 4 + g) * 8) ^ ((l & 7) << 3))];
      #pragma unroll
      for (int mct = 0; mct < 2; ++mct) {
        f32x4 z = {0.f, 0.f, 0.f, 0.f};
        #pragma unroll
        for (int ks = 0; ks < 2; ++ks) z = MFMA16(gf[mct][ks], avf[ks], z);
        #pragma unroll
        for (int r = 0; r < 4; ++r) {
          const int m = w * 32 + mct * 16 + g * 4 + r;
          out[(size_t)(b * 128 + m) * LTOT + l0 + l] =
              (z[r] - mean_[mct][r]) * rsig_[mct][r];
        }
      }
    }
  }
}

extern "C" void kernel_launch(void* const* d_in, const int* in_sizes, int n_in,
                              void* d_out, int out_size, void* d_ws, size_t ws_size,
                              hipStream_t stream)
{
  const float* x  = (const float*)d_in[0];
  const float* WA = (const float*)d_in[1];
  const float* bA = (const float*)d_in[2];
  const float* WB = (const float*)d_in[3];
  const float* bB = (const float*)d_in[4];
  const float* WV = (const float*)d_in[5];
  const float* bV = (const float*)d_in[6];
  float* out = (float*)d_out;

  // layout uses the old float-count offsets (oversized is fine)
  float* w = (float*)d_ws;
  f16*   mpart  = (f16*)w;                  // 2*432*8192 f16 (region sized as f32)
  float* mpart2 = w + 7077888;              // 2*8*8192 f32
  float* separt = mpart2 + 131072;          // 2*432*64
  float* msum   = separt + 55296;           // 2*8192
  float* sesum  = msum + 16384;             // 128
  float* g32    = sesum + 128;              // 2*8192
  f16*   g16f   = (f16*)(g32 + 16384);      // 16,384 f16
  f16*   av_g   = g16f + 16384;             // 2*L*64 f16 = 14,155,776
  f16*   cpart  = (f16*)(av_g + 14155776);  // 2*216*4096 f16 (region sized as f32)
  float* mupart = (float*)(av_g + 14155776) + 1769472;  // 2*216*64
  float* csum   = mupart + 27648;           // 2*4096
  float* musum  = csum + 8192;              // 128
  float* mr     = musum + 128;              // 512

  p1_proj_m<<<dim3(432, 2), 256, 0, stream>>>(x, WB, bB, WV, bV, av_g, mpart, separt);
  ka_red_cov<<<dim3(473, 2), 256, 0, stream>>>(mpart, separt, mpart2, sesum,
                                               av_g, cpart, mupart);
  kb_red<<<dim3(97, 2), 256, 0, stream>>>(mpart2, msum, cpart, mupart, csum, musum);
  p2b<<<dim3(32, 2), 256, 0, stream>>>(WA, bA, msum, sesum, g32, g16f);
  p4b<<<dim3(4, 2), 256, 0, stream>>>(csum, musum, g32, mr);
  p5_z<<<dim3(432, 2), 256, 0, stream>>>(av_g, g16f, mr, out);
}